// Round 1
// baseline (1532.589 us; speedup 1.0000x reference)
//
#include <hip/hip_runtime.h>

#define N_NODES 50000
#define N_EDGES 800000
#define IN_CH   256
#define OUT_CH  128

// ---------------- transpose W [128][256] -> Wt [256][128] ----------------
__global__ __launch_bounds__(256) void transpose_w(const float* __restrict__ W,
                                                   float* __restrict__ Wt) {
    int idx = blockIdx.x * 256 + threadIdx.x;   // over 128*256 = 32768
    if (idx < OUT_CH * IN_CH) {
        int o = idx >> 8;        // / IN_CH (=256)
        int k = idx & 255;
        Wt[k * OUT_CH + o] = W[idx];
    }
}

// ---------------- GEMM: lin[n][o] = sum_k x[n][k] * Wt[k][o] + b[o] ------
#define BM 64
#define BK 32
__global__ __launch_bounds__(256) void gemm_xwt(const float* __restrict__ x,
                                                const float* __restrict__ Wt,
                                                const float* __restrict__ bias,
                                                float* __restrict__ lin) {
    __shared__ float xs[BK][BM];        // [kk][row]  (transposed stage)
    __shared__ float wsh[BK][OUT_CH];   // [kk][col]

    const int tid  = threadIdx.x;
    const int m0   = blockIdx.x * BM;
    const int col0 = (tid & 31) * 4;    // 4 consecutive cols
    const int r0   = (tid >> 5) * 8;    // 8 consecutive rows

    float acc[8][4];
#pragma unroll
    for (int r = 0; r < 8; ++r)
#pragma unroll
        for (int c = 0; c < 4; ++c) acc[r][c] = 0.0f;

    for (int k0 = 0; k0 < IN_CH; k0 += BK) {
        // stage x tile: 64 rows x 32 k  (512 float4, 2 per thread)
#pragma unroll
        for (int i = 0; i < 2; ++i) {
            int idx = i * 256 + tid;         // 0..511
            int row = idx >> 3;              // 8 float4 per row
            int c4  = idx & 7;
            int gr  = m0 + row;
            float4 v = make_float4(0.f, 0.f, 0.f, 0.f);
            if (gr < N_NODES)
                v = *(const float4*)&x[(size_t)gr * IN_CH + k0 + c4 * 4];
            xs[c4 * 4 + 0][row] = v.x;
            xs[c4 * 4 + 1][row] = v.y;
            xs[c4 * 4 + 2][row] = v.z;
            xs[c4 * 4 + 3][row] = v.w;
        }
        // stage W tile: 32 k x 128 cols (1024 float4, 4 per thread), same layout
#pragma unroll
        for (int i = 0; i < 4; ++i) {
            int idx = i * 256 + tid;         // 0..1023
            int kk  = idx >> 5;              // 32 float4 per k-row
            int c4  = idx & 31;
            float4 v = *(const float4*)&Wt[(size_t)(k0 + kk) * OUT_CH + c4 * 4];
            *(float4*)&wsh[kk][c4 * 4] = v;
        }
        __syncthreads();

#pragma unroll
        for (int kk = 0; kk < BK; ++kk) {
            const float4 a0 = *(const float4*)&xs[kk][r0];
            const float4 a1 = *(const float4*)&xs[kk][r0 + 4];
            const float4 w4 = *(const float4*)&wsh[kk][col0];
            float a[8] = {a0.x, a0.y, a0.z, a0.w, a1.x, a1.y, a1.z, a1.w};
#pragma unroll
            for (int r = 0; r < 8; ++r) {
                acc[r][0] += a[r] * w4.x;
                acc[r][1] += a[r] * w4.y;
                acc[r][2] += a[r] * w4.z;
                acc[r][3] += a[r] * w4.w;
            }
        }
        __syncthreads();
    }

    const float4 bv = *(const float4*)&bias[col0];
#pragma unroll
    for (int r = 0; r < 8; ++r) {
        int row = m0 + r0 + r;
        if (row < N_NODES) {
            float4 o;
            o.x = acc[r][0] + bv.x;
            o.y = acc[r][1] + bv.y;
            o.z = acc[r][2] + bv.z;
            o.w = acc[r][3] + bv.w;
            *(float4*)&lin[(size_t)row * OUT_CH + col0] = o;
        }
    }
}

// ---------------- scatter-add lin[src] into sum[dst], count dst ----------
__global__ __launch_bounds__(256) void scatter_edges(const int* __restrict__ src,
                                                     const int* __restrict__ dst,
                                                     const float* __restrict__ lin,
                                                     float* __restrict__ sum,
                                                     int* __restrict__ cnt) {
    int e = blockIdx.x * 8 + (threadIdx.x >> 5);   // 8 edges per 256-thread block
    if (e >= N_EDGES) return;
    int l = threadIdx.x & 31;
    int s = src[e];
    int d = dst[e];
    if ((unsigned)s >= N_NODES || (unsigned)d >= N_NODES) return;
    if (l == 0) atomicAdd(&cnt[d], 1);
    float4 v = *(const float4*)&lin[(size_t)s * OUT_CH + l * 4];
    float* dp = &sum[(size_t)d * OUT_CH + l * 4];
    atomicAdd(dp + 0, v.x);
    atomicAdd(dp + 1, v.y);
    atomicAdd(dp + 2, v.z);
    atomicAdd(dp + 3, v.w);
}

// ---------------- divide by max(count, 1) --------------------------------
__global__ __launch_bounds__(256) void div_cnt(float* __restrict__ out,
                                               const int* __restrict__ cnt) {
    int i4 = blockIdx.x * 256 + threadIdx.x;       // over (N*128)/4 = 1.6M float4
    if (i4 >= N_NODES * OUT_CH / 4) return;
    int node = i4 >> 5;                            // (i4*4) / 128
    int c = cnt[node];
    float inv = 1.0f / (float)(c > 1 ? c : 1);
    float4 v = ((const float4*)out)[i4];
    v.x *= inv; v.y *= inv; v.z *= inv; v.w *= inv;
    ((float4*)out)[i4] = v;
}

extern "C" void kernel_launch(void* const* d_in, const int* in_sizes, int n_in,
                              void* d_out, int out_size, void* d_ws, size_t ws_size,
                              hipStream_t stream) {
    const float* x  = (const float*)d_in[0];
    const int*   ei = (const int*)d_in[1];     // [2][E]: src then dst
    const float* W  = (const float*)d_in[2];
    const float* b  = (const float*)d_in[3];
    float* out = (float*)d_out;

    const int* src = ei;
    const int* dst = ei + N_EDGES;

    // workspace layout: lin (25.6MB) | Wt (512KB) | cnt (200KB)
    char* ws = (char*)d_ws;
    float* lin = (float*)ws;
    float* Wt  = (float*)(ws + (size_t)N_NODES * OUT_CH * sizeof(float));
    int*   cnt = (int*)(ws + (size_t)N_NODES * OUT_CH * sizeof(float)
                           + (size_t)IN_CH * OUT_CH * sizeof(float));

    hipMemsetAsync(d_out, 0, (size_t)N_NODES * OUT_CH * sizeof(float), stream);
    hipMemsetAsync(cnt, 0, (size_t)N_NODES * sizeof(int), stream);

    transpose_w<<<(OUT_CH * IN_CH + 255) / 256, 256, 0, stream>>>(W, Wt);
    gemm_xwt<<<(N_NODES + BM - 1) / BM, 256, 0, stream>>>(x, Wt, b, lin);
    scatter_edges<<<(N_EDGES * 32 + 255) / 256, 256, 0, stream>>>(src, dst, lin, out, cnt);
    div_cnt<<<(N_NODES * OUT_CH / 4 + 255) / 256, 256, 0, stream>>>(out, cnt);
}

// Round 2
// 330.835 us; speedup vs baseline: 4.6325x; 4.6325x over previous
//
#include <hip/hip_runtime.h>

#define N_NODES 50000
#define N_EDGES 800000
#define IN_CH   256
#define OUT_CH  128

// ---------------- transpose W [128][256] -> Wt [256][128] ----------------
__global__ __launch_bounds__(256) void transpose_w(const float* __restrict__ W,
                                                   float* __restrict__ Wt) {
    int idx = blockIdx.x * 256 + threadIdx.x;   // over 128*256 = 32768
    if (idx < OUT_CH * IN_CH) {
        int o = idx >> 8;        // / IN_CH (=256)
        int k = idx & 255;
        Wt[k * OUT_CH + o] = W[idx];
    }
}

// ---------------- GEMM: lin[n][o] = sum_k x[n][k] * Wt[k][o] + b[o] ------
#define BM 64
#define BK 32
__global__ __launch_bounds__(256) void gemm_xwt(const float* __restrict__ x,
                                                const float* __restrict__ Wt,
                                                const float* __restrict__ bias,
                                                float* __restrict__ lin) {
    __shared__ float xs[BK][BM];        // [kk][row]  (transposed stage)
    __shared__ float wsh[BK][OUT_CH];   // [kk][col]

    const int tid  = threadIdx.x;
    const int m0   = blockIdx.x * BM;
    const int col0 = (tid & 31) * 4;    // 4 consecutive cols
    const int r0   = (tid >> 5) * 8;    // 8 consecutive rows

    float acc[8][4];
#pragma unroll
    for (int r = 0; r < 8; ++r)
#pragma unroll
        for (int c = 0; c < 4; ++c) acc[r][c] = 0.0f;

    for (int k0 = 0; k0 < IN_CH; k0 += BK) {
#pragma unroll
        for (int i = 0; i < 2; ++i) {
            int idx = i * 256 + tid;         // 0..511
            int row = idx >> 3;              // 8 float4 per row
            int c4  = idx & 7;
            int gr  = m0 + row;
            float4 v = make_float4(0.f, 0.f, 0.f, 0.f);
            if (gr < N_NODES)
                v = *(const float4*)&x[(size_t)gr * IN_CH + k0 + c4 * 4];
            xs[c4 * 4 + 0][row] = v.x;
            xs[c4 * 4 + 1][row] = v.y;
            xs[c4 * 4 + 2][row] = v.z;
            xs[c4 * 4 + 3][row] = v.w;
        }
#pragma unroll
        for (int i = 0; i < 4; ++i) {
            int idx = i * 256 + tid;         // 0..1023
            int kk  = idx >> 5;              // 32 float4 per k-row
            int c4  = idx & 31;
            float4 v = *(const float4*)&Wt[(size_t)(k0 + kk) * OUT_CH + c4 * 4];
            *(float4*)&wsh[kk][c4 * 4] = v;
        }
        __syncthreads();

#pragma unroll
        for (int kk = 0; kk < BK; ++kk) {
            const float4 a0 = *(const float4*)&xs[kk][r0];
            const float4 a1 = *(const float4*)&xs[kk][r0 + 4];
            const float4 w4 = *(const float4*)&wsh[kk][col0];
            float a[8] = {a0.x, a0.y, a0.z, a0.w, a1.x, a1.y, a1.z, a1.w};
#pragma unroll
            for (int r = 0; r < 8; ++r) {
                acc[r][0] += a[r] * w4.x;
                acc[r][1] += a[r] * w4.y;
                acc[r][2] += a[r] * w4.z;
                acc[r][3] += a[r] * w4.w;
            }
        }
        __syncthreads();
    }

    const float4 bv = *(const float4*)&bias[col0];
#pragma unroll
    for (int r = 0; r < 8; ++r) {
        int row = m0 + r0 + r;
        if (row < N_NODES) {
            float4 o;
            o.x = acc[r][0] + bv.x;
            o.y = acc[r][1] + bv.y;
            o.z = acc[r][2] + bv.z;
            o.w = acc[r][3] + bv.w;
            *(float4*)&lin[(size_t)row * OUT_CH + col0] = o;
        }
    }
}

// ---------------- histogram of dst -------------------------------------
__global__ __launch_bounds__(256) void hist_dst(const int* __restrict__ dst,
                                                int* __restrict__ cnt) {
    int e = blockIdx.x * 256 + threadIdx.x;
    if (e >= N_EDGES) return;
    int d = dst[e];
    if ((unsigned)d < N_NODES) atomicAdd(&cnt[d], 1);
}

// ---------------- single-block exclusive scan of cnt -> off, cursor ------
__global__ __launch_bounds__(1024) void scan_cnt(const int* __restrict__ cnt,
                                                 int* __restrict__ off,
                                                 int* __restrict__ cursor) {
    __shared__ int wsums[16];
    __shared__ int s_carry;
    const int tid = threadIdx.x;
    const int lane = tid & 63;
    const int wid = tid >> 6;
    if (tid == 0) s_carry = 0;
    __syncthreads();
    for (int base = 0; base < N_NODES; base += 1024) {
        int i = base + tid;
        int v = (i < N_NODES) ? cnt[i] : 0;
        int incl = v;
#pragma unroll
        for (int s = 1; s < 64; s <<= 1) {
            int t = __shfl_up(incl, s, 64);
            if (lane >= s) incl += t;
        }
        if (lane == 63) wsums[wid] = incl;
        __syncthreads();
        if (tid < 16) {
            int w = wsums[tid];
#pragma unroll
            for (int s = 1; s < 16; s <<= 1) {
                int t = __shfl_up(w, s, 64);
                if (tid >= s) w += t;
            }
            wsums[tid] = w;
        }
        __syncthreads();
        int carry = s_carry;
        int waveoff = (wid > 0) ? wsums[wid - 1] : 0;
        int excl = carry + waveoff + incl - v;
        if (i < N_NODES) { off[i] = excl; cursor[i] = excl; }
        __syncthreads();   // everyone read s_carry before update
        if (tid == 0) s_carry = carry + wsums[15];
        __syncthreads();
    }
    if (tid == 0) off[N_NODES] = s_carry;
}

// ---------------- fill: bucket src by dst --------------------------------
__global__ __launch_bounds__(256) void fill_csr(const int* __restrict__ src,
                                                const int* __restrict__ dst,
                                                int* __restrict__ cursor,
                                                int* __restrict__ srcs_sorted) {
    int e = blockIdx.x * 256 + threadIdx.x;
    if (e >= N_EDGES) return;
    int d = dst[e];
    int s = src[e];
    if ((unsigned)d >= N_NODES || (unsigned)s >= N_NODES) return;
    int pos = atomicAdd(&cursor[d], 1);
    srcs_sorted[pos] = s;
}

// ---------------- per-node gather + mean ---------------------------------
__global__ __launch_bounds__(256) void gather_mean(const int* __restrict__ srcs_sorted,
                                                   const int* __restrict__ off,
                                                   const float* __restrict__ lin,
                                                   float* __restrict__ out) {
    int n = blockIdx.x * 8 + (threadIdx.x >> 5);   // 8 nodes / block, 32 lanes / node
    if (n >= N_NODES) return;
    const int l = threadIdx.x & 31;
    const int beg = off[n];
    const int end = off[n + 1];

    float ax = 0.f, ay = 0.f, az = 0.f, aw = 0.f;
    float bx = 0.f, by = 0.f, bz = 0.f, bw = 0.f;
    int i = beg;
    for (; i + 1 < end; i += 2) {
        int s0 = srcs_sorted[i];
        int s1 = srcs_sorted[i + 1];
        float4 v0 = *(const float4*)&lin[(size_t)s0 * OUT_CH + l * 4];
        float4 v1 = *(const float4*)&lin[(size_t)s1 * OUT_CH + l * 4];
        ax += v0.x; ay += v0.y; az += v0.z; aw += v0.w;
        bx += v1.x; by += v1.y; bz += v1.z; bw += v1.w;
    }
    if (i < end) {
        int s0 = srcs_sorted[i];
        float4 v0 = *(const float4*)&lin[(size_t)s0 * OUT_CH + l * 4];
        ax += v0.x; ay += v0.y; az += v0.z; aw += v0.w;
    }
    int deg = end - beg;
    float inv = 1.0f / (float)(deg > 1 ? deg : 1);
    float4 o;
    o.x = (ax + bx) * inv;
    o.y = (ay + by) * inv;
    o.z = (az + bz) * inv;
    o.w = (aw + bw) * inv;
    *(float4*)&out[(size_t)n * OUT_CH + l * 4] = o;
}

extern "C" void kernel_launch(void* const* d_in, const int* in_sizes, int n_in,
                              void* d_out, int out_size, void* d_ws, size_t ws_size,
                              hipStream_t stream) {
    const float* x  = (const float*)d_in[0];
    const int*   ei = (const int*)d_in[1];     // [2][E]: src then dst
    const float* W  = (const float*)d_in[2];
    const float* b  = (const float*)d_in[3];
    float* out = (float*)d_out;

    const int* src = ei;
    const int* dst = ei + N_EDGES;

    // workspace layout: lin (25.6MB) | Wt (128KB) | cnt | off(N+1) | cursor | srcs_sorted (3.2MB)
    char* ws = (char*)d_ws;
    float* lin    = (float*)ws;                 ws += (size_t)N_NODES * OUT_CH * sizeof(float);
    float* Wt     = (float*)ws;                 ws += (size_t)IN_CH * OUT_CH * sizeof(float);
    int*   cnt    = (int*)ws;                   ws += (size_t)N_NODES * sizeof(int);
    int*   off    = (int*)ws;                   ws += (size_t)(N_NODES + 1) * sizeof(int);
    int*   cursor = (int*)ws;                   ws += (size_t)N_NODES * sizeof(int);
    int*   srcs_sorted = (int*)ws;

    hipMemsetAsync(cnt, 0, (size_t)N_NODES * sizeof(int), stream);

    transpose_w<<<(OUT_CH * IN_CH + 255) / 256, 256, 0, stream>>>(W, Wt);
    gemm_xwt<<<(N_NODES + BM - 1) / BM, 256, 0, stream>>>(x, Wt, b, lin);
    hist_dst<<<(N_EDGES + 255) / 256, 256, 0, stream>>>(dst, cnt);
    scan_cnt<<<1, 1024, 0, stream>>>(cnt, off, cursor);
    fill_csr<<<(N_EDGES + 255) / 256, 256, 0, stream>>>(src, dst, cursor, srcs_sorted);
    gather_mean<<<(N_NODES + 7) / 8, 256, 0, stream>>>(srcs_sorted, off, lin, out);
}

// Round 3
// 239.240 us; speedup vs baseline: 6.4061x; 1.3829x over previous
//
#include <hip/hip_runtime.h>

#define N_NODES 50000
#define N_EDGES 800000
#define IN_CH   256
#define OUT_CH  128

typedef __attribute__((ext_vector_type(8))) short short8;   // 8 bf16 (4 VGPRs)
typedef __attribute__((ext_vector_type(4))) float f32x4;

__device__ __forceinline__ short f2bf(float f) {
    unsigned u = __float_as_uint(f);
    unsigned r = (u + 0x7fffu + ((u >> 16) & 1u)) >> 16;    // RNE
    return (short)r;
}

// ---------------- convert W fp32 -> bf16 (layout [out_ch][in_ch] = B^T) --
__global__ __launch_bounds__(256) void convert_w(const float* __restrict__ W,
                                                 short* __restrict__ Wbf) {
    int idx = blockIdx.x * 256 + threadIdx.x;
    if (idx < OUT_CH * IN_CH) Wbf[idx] = f2bf(W[idx]);
}

// ---------------- MFMA GEMM: linbf[m][n] = bf16( x[m][:]*W[n][:] + b[n] )
#define GBM 128
#define GBK 32
#define LDK 40   // padded row length (bf16 elems); 80B stride keeps 16B align
__global__ __launch_bounds__(256) void gemm_mfma(const float* __restrict__ x,
                                                 const short* __restrict__ Wbf,
                                                 const float* __restrict__ bias,
                                                 short* __restrict__ linbf) {
    __shared__ short As[GBM * LDK];   // A tile: [m][k]
    __shared__ short Bs[OUT_CH * LDK];// B tile: [n][k]

    const int tid = threadIdx.x;
    const int m0  = blockIdx.x * GBM;
    const int w    = tid >> 6;
    const int lane = tid & 63;
    const int lm   = lane & 15;
    const int lq   = lane >> 4;
    const int wrow = (w >> 1) * 64;
    const int wcol = (w & 1) * 64;

    f32x4 acc[4][4];
#pragma unroll
    for (int i = 0; i < 4; ++i)
#pragma unroll
        for (int j = 0; j < 4; ++j) acc[i][j] = (f32x4)(0.0f);

    const int srow = tid >> 1;        // staging row (0..127)
    const int shalf = tid & 1;        // which 16-k half

    for (int k0 = 0; k0 < IN_CH; k0 += GBK) {
        // stage A: 128 rows x 32 k, fp32 -> bf16
        {
            float4 v0 = make_float4(0.f,0.f,0.f,0.f), v1 = v0, v2 = v0, v3 = v0;
            if (m0 + srow < N_NODES) {
                const float* xp = x + (size_t)(m0 + srow) * IN_CH + k0 + shalf * 16;
                v0 = ((const float4*)xp)[0];
                v1 = ((const float4*)xp)[1];
                v2 = ((const float4*)xp)[2];
                v3 = ((const float4*)xp)[3];
            }
            short8 s0, s1;
            s0[0]=f2bf(v0.x); s0[1]=f2bf(v0.y); s0[2]=f2bf(v0.z); s0[3]=f2bf(v0.w);
            s0[4]=f2bf(v1.x); s0[5]=f2bf(v1.y); s0[6]=f2bf(v1.z); s0[7]=f2bf(v1.w);
            s1[0]=f2bf(v2.x); s1[1]=f2bf(v2.y); s1[2]=f2bf(v2.z); s1[3]=f2bf(v2.w);
            s1[4]=f2bf(v3.x); s1[5]=f2bf(v3.y); s1[6]=f2bf(v3.z); s1[7]=f2bf(v3.w);
            *(short8*)&As[srow * LDK + shalf * 16]     = s0;
            *(short8*)&As[srow * LDK + shalf * 16 + 8] = s1;
        }
        // stage B: 128 n x 32 k (already bf16)
        {
            const short* wp = Wbf + (size_t)srow * IN_CH + k0 + shalf * 16;
            *(short8*)&Bs[srow * LDK + shalf * 16]     = ((const short8*)wp)[0];
            *(short8*)&Bs[srow * LDK + shalf * 16 + 8] = ((const short8*)wp)[1];
        }
        __syncthreads();

        short8 af[4], bfr[4];
#pragma unroll
        for (int rt = 0; rt < 4; ++rt)
            af[rt] = *(const short8*)&As[(wrow + rt * 16 + lm) * LDK + lq * 8];
#pragma unroll
        for (int ct = 0; ct < 4; ++ct)
            bfr[ct] = *(const short8*)&Bs[(wcol + ct * 16 + lm) * LDK + lq * 8];
#pragma unroll
        for (int rt = 0; rt < 4; ++rt)
#pragma unroll
            for (int ct = 0; ct < 4; ++ct)
                acc[rt][ct] = __builtin_amdgcn_mfma_f32_16x16x32_bf16(
                    af[rt], bfr[ct], acc[rt][ct], 0, 0, 0);
        __syncthreads();
    }

    // epilogue: D row = lq*4 + r, col = lm
#pragma unroll
    for (int ct = 0; ct < 4; ++ct) {
        int gcol = wcol + ct * 16 + lm;
        float bv = bias[gcol];
#pragma unroll
        for (int rt = 0; rt < 4; ++rt) {
#pragma unroll
            for (int r = 0; r < 4; ++r) {
                int grow = m0 + wrow + rt * 16 + lq * 4 + r;
                if (grow < N_NODES)
                    linbf[(size_t)grow * OUT_CH + gcol] = f2bf(acc[rt][ct][r] + bv);
            }
        }
    }
}

// ---------------- histogram of dst -------------------------------------
__global__ __launch_bounds__(256) void hist_dst(const int* __restrict__ dst,
                                                int* __restrict__ cnt) {
    int e = blockIdx.x * 256 + threadIdx.x;
    if (e >= N_EDGES) return;
    int d = dst[e];
    if ((unsigned)d < N_NODES) atomicAdd(&cnt[d], 1);
}

// ---------------- hierarchical scan ------------------------------------
#define SCAN_BLK 1024
#define SCAN_NBLK ((N_NODES + SCAN_BLK - 1) / SCAN_BLK)   // 49

__global__ __launch_bounds__(SCAN_BLK) void scan_partial(const int* __restrict__ cnt,
                                                         int* __restrict__ bsum) {
    __shared__ int wsum[16];
    int tid = threadIdx.x;
    int i = blockIdx.x * SCAN_BLK + tid;
    int v = (i < N_NODES) ? cnt[i] : 0;
#pragma unroll
    for (int s = 32; s >= 1; s >>= 1) v += __shfl_down(v, s, 64);
    if ((tid & 63) == 0) wsum[tid >> 6] = v;
    __syncthreads();
    if (tid == 0) {
        int t = 0;
#pragma unroll
        for (int k = 0; k < 16; ++k) t += wsum[k];
        bsum[blockIdx.x] = t;
    }
}

__global__ __launch_bounds__(64) void scan_boff(const int* __restrict__ bsum,
                                                int* __restrict__ boff,
                                                int* __restrict__ off) {
    int tid = threadIdx.x;
    int v = (tid < SCAN_NBLK) ? bsum[tid] : 0;
    int incl = v;
#pragma unroll
    for (int s = 1; s < 64; s <<= 1) {
        int t = __shfl_up(incl, s, 64);
        if (tid >= s) incl += t;
    }
    if (tid < SCAN_NBLK) boff[tid] = incl - v;
    if (tid == 63) off[N_NODES] = incl;
}

__global__ __launch_bounds__(SCAN_BLK) void scan_apply(const int* __restrict__ cnt,
                                                       const int* __restrict__ boff,
                                                       int* __restrict__ off,
                                                       int* __restrict__ cursor) {
    __shared__ int wsums[16];
    int tid = threadIdx.x;
    int lane = tid & 63;
    int wid = tid >> 6;
    int i = blockIdx.x * SCAN_BLK + tid;
    int v = (i < N_NODES) ? cnt[i] : 0;
    int incl = v;
#pragma unroll
    for (int s = 1; s < 64; s <<= 1) {
        int t = __shfl_up(incl, s, 64);
        if (lane >= s) incl += t;
    }
    if (lane == 63) wsums[wid] = incl;
    __syncthreads();
    if (tid < 16) {
        int w = wsums[tid];
#pragma unroll
        for (int s = 1; s < 16; s <<= 1) {
            int t = __shfl_up(w, s, 64);
            if (tid >= s) w += t;
        }
        wsums[tid] = w;
    }
    __syncthreads();
    int excl = boff[blockIdx.x] + (wid > 0 ? wsums[wid - 1] : 0) + incl - v;
    if (i < N_NODES) { off[i] = excl; cursor[i] = excl; }
}

// ---------------- fill: bucket src by dst --------------------------------
__global__ __launch_bounds__(256) void fill_csr(const int* __restrict__ src,
                                                const int* __restrict__ dst,
                                                int* __restrict__ cursor,
                                                int* __restrict__ srcs_sorted) {
    int e = blockIdx.x * 256 + threadIdx.x;
    if (e >= N_EDGES) return;
    int d = dst[e];
    int s = src[e];
    if ((unsigned)d >= N_NODES || (unsigned)s >= N_NODES) return;
    int pos = atomicAdd(&cursor[d], 1);
    srcs_sorted[pos] = s;
}

// ---------------- per-node gather + mean (bf16 lin) ----------------------
__global__ __launch_bounds__(256) void gather_mean(const int* __restrict__ srcs_sorted,
                                                   const int* __restrict__ off,
                                                   const short* __restrict__ linbf,
                                                   float* __restrict__ out) {
    int n = blockIdx.x * 16 + (threadIdx.x >> 4);   // 16 nodes / block, 16 lanes / node
    if (n >= N_NODES) return;
    const int l = threadIdx.x & 15;                 // lane handles 8 bf16 = 16B
    const int beg = off[n];
    const int end = off[n + 1];

    float a[8];
#pragma unroll
    for (int j = 0; j < 8; ++j) a[j] = 0.0f;

    int i = beg;
    for (; i + 1 < end; i += 2) {
        int s0 = srcs_sorted[i];
        int s1 = srcs_sorted[i + 1];
        uint4 u0 = *(const uint4*)&linbf[(size_t)s0 * OUT_CH + l * 8];
        uint4 u1 = *(const uint4*)&linbf[(size_t)s1 * OUT_CH + l * 8];
        const unsigned* p0 = (const unsigned*)&u0;
        const unsigned* p1 = (const unsigned*)&u1;
#pragma unroll
        for (int j = 0; j < 4; ++j) {
            a[2*j]   += __uint_as_float(p0[j] << 16) + __uint_as_float(p1[j] << 16);
            a[2*j+1] += __uint_as_float(p0[j] & 0xffff0000u) + __uint_as_float(p1[j] & 0xffff0000u);
        }
    }
    if (i < end) {
        int s0 = srcs_sorted[i];
        uint4 u0 = *(const uint4*)&linbf[(size_t)s0 * OUT_CH + l * 8];
        const unsigned* p0 = (const unsigned*)&u0;
#pragma unroll
        for (int j = 0; j < 4; ++j) {
            a[2*j]   += __uint_as_float(p0[j] << 16);
            a[2*j+1] += __uint_as_float(p0[j] & 0xffff0000u);
        }
    }
    int deg = end - beg;
    float inv = 1.0f / (float)(deg > 1 ? deg : 1);
    float4 o0, o1;
    o0.x = a[0]*inv; o0.y = a[1]*inv; o0.z = a[2]*inv; o0.w = a[3]*inv;
    o1.x = a[4]*inv; o1.y = a[5]*inv; o1.z = a[6]*inv; o1.w = a[7]*inv;
    float* op = &out[(size_t)n * OUT_CH + l * 8];
    ((float4*)op)[0] = o0;
    ((float4*)op)[1] = o1;
}

extern "C" void kernel_launch(void* const* d_in, const int* in_sizes, int n_in,
                              void* d_out, int out_size, void* d_ws, size_t ws_size,
                              hipStream_t stream) {
    const float* x  = (const float*)d_in[0];
    const int*   ei = (const int*)d_in[1];     // [2][E]: src then dst
    const float* W  = (const float*)d_in[2];
    const float* b  = (const float*)d_in[3];
    float* out = (float*)d_out;

    const int* src = ei;
    const int* dst = ei + N_EDGES;

    // workspace layout
    char* ws = (char*)d_ws;
    short* linbf = (short*)ws;                  ws += (size_t)N_NODES * OUT_CH * sizeof(short);   // 12.8 MB
    short* Wbf   = (short*)ws;                  ws += (size_t)IN_CH * OUT_CH * sizeof(short);     // 64 KB
    int* cnt     = (int*)ws;                    ws += (size_t)N_NODES * sizeof(int);
    int* off     = (int*)ws;                    ws += (size_t)(N_NODES + 1) * sizeof(int) + 252;  // pad
    int* cursor  = (int*)ws;                    ws += (size_t)N_NODES * sizeof(int);
    int* bsum    = (int*)ws;                    ws += 64 * sizeof(int);
    int* boff    = (int*)ws;                    ws += 64 * sizeof(int);
    int* srcs_sorted = (int*)ws;

    hipMemsetAsync(cnt, 0, (size_t)N_NODES * sizeof(int), stream);

    convert_w<<<(OUT_CH * IN_CH + 255) / 256, 256, 0, stream>>>(W, Wbf);
    gemm_mfma<<<(N_NODES + GBM - 1) / GBM, 256, 0, stream>>>(x, Wbf, b, linbf);
    hist_dst<<<(N_EDGES + 255) / 256, 256, 0, stream>>>(dst, cnt);
    scan_partial<<<SCAN_NBLK, SCAN_BLK, 0, stream>>>(cnt, bsum);
    scan_boff<<<1, 64, 0, stream>>>(bsum, boff, off);
    scan_apply<<<SCAN_NBLK, SCAN_BLK, 0, stream>>>(cnt, boff, off, cursor);
    fill_csr<<<(N_EDGES + 255) / 256, 256, 0, stream>>>(src, dst, cursor, srcs_sorted);
    gather_mean<<<(N_NODES + 15) / 16, 256, 0, stream>>>(srcs_sorted, off, linbf, out);
}

// Round 4
// 173.612 us; speedup vs baseline: 8.8277x; 1.3780x over previous
//
#include <hip/hip_runtime.h>

#define N_NODES 50000
#define N_EDGES 800000
#define IN_CH   256
#define OUT_CH  128

#define NB        391          // coarse buckets of 128 nodes: ceil(50000/128)
#define CAP       3072         // record capacity per bucket (mean 2048, sd ~45)
#define L1_CHUNK  2048
#define L1_BLOCKS ((N_EDGES + L1_CHUNK - 1) / L1_CHUNK)   // 391

typedef __attribute__((ext_vector_type(8))) short short8;   // 8 bf16 (4 VGPRs)
typedef __attribute__((ext_vector_type(4))) float f32x4;

__device__ __forceinline__ short f2bf(float f) {
    unsigned u = __float_as_uint(f);
    unsigned r = (u + 0x7fffu + ((u >> 16) & 1u)) >> 16;    // RNE
    return (short)r;
}

// ---------------- MFMA GEMM: linbf[m][n] = bf16( x[m][:].W[n][:] + b[n] )
// W fp32 [128][256] is exactly B^T [n][k]; convert fused into staging.
#define GBM 128
#define GBK 32
#define LDK 40   // padded row length (bf16 elems); 80B stride keeps 16B align
__global__ __launch_bounds__(256) void gemm_mfma(const float* __restrict__ x,
                                                 const float* __restrict__ W,
                                                 const float* __restrict__ bias,
                                                 short* __restrict__ linbf) {
    __shared__ short As[GBM * LDK];    // A tile: [m][k]
    __shared__ short Bs[OUT_CH * LDK]; // B tile: [n][k]

    const int tid = threadIdx.x;
    const int m0  = blockIdx.x * GBM;
    const int w    = tid >> 6;
    const int lane = tid & 63;
    const int lm   = lane & 15;
    const int lq   = lane >> 4;
    const int wrow = (w >> 1) * 64;
    const int wcol = (w & 1) * 64;

    f32x4 acc[4][4];
#pragma unroll
    for (int i = 0; i < 4; ++i)
#pragma unroll
        for (int j = 0; j < 4; ++j) acc[i][j] = (f32x4)(0.0f);

    const int srow  = tid >> 1;       // staging row (0..127)
    const int shalf = tid & 1;        // which 16-k half

    for (int k0 = 0; k0 < IN_CH; k0 += GBK) {
        // stage A: 128 rows x 32 k, fp32 -> bf16
        {
            float4 v0 = make_float4(0.f,0.f,0.f,0.f), v1 = v0, v2 = v0, v3 = v0;
            if (m0 + srow < N_NODES) {
                const float* xp = x + (size_t)(m0 + srow) * IN_CH + k0 + shalf * 16;
                v0 = ((const float4*)xp)[0];
                v1 = ((const float4*)xp)[1];
                v2 = ((const float4*)xp)[2];
                v3 = ((const float4*)xp)[3];
            }
            short8 s0, s1;
            s0[0]=f2bf(v0.x); s0[1]=f2bf(v0.y); s0[2]=f2bf(v0.z); s0[3]=f2bf(v0.w);
            s0[4]=f2bf(v1.x); s0[5]=f2bf(v1.y); s0[6]=f2bf(v1.z); s0[7]=f2bf(v1.w);
            s1[0]=f2bf(v2.x); s1[1]=f2bf(v2.y); s1[2]=f2bf(v2.z); s1[3]=f2bf(v2.w);
            s1[4]=f2bf(v3.x); s1[5]=f2bf(v3.y); s1[6]=f2bf(v3.z); s1[7]=f2bf(v3.w);
            *(short8*)&As[srow * LDK + shalf * 16]     = s0;
            *(short8*)&As[srow * LDK + shalf * 16 + 8] = s1;
        }
        // stage B: 128 n x 32 k, fp32 -> bf16 (fused convert)
        {
            const float* wp = W + (size_t)srow * IN_CH + k0 + shalf * 16;
            float4 v0 = ((const float4*)wp)[0];
            float4 v1 = ((const float4*)wp)[1];
            float4 v2 = ((const float4*)wp)[2];
            float4 v3 = ((const float4*)wp)[3];
            short8 s0, s1;
            s0[0]=f2bf(v0.x); s0[1]=f2bf(v0.y); s0[2]=f2bf(v0.z); s0[3]=f2bf(v0.w);
            s0[4]=f2bf(v1.x); s0[5]=f2bf(v1.y); s0[6]=f2bf(v1.z); s0[7]=f2bf(v1.w);
            s1[0]=f2bf(v2.x); s1[1]=f2bf(v2.y); s1[2]=f2bf(v2.z); s1[3]=f2bf(v2.w);
            s1[4]=f2bf(v3.x); s1[5]=f2bf(v3.y); s1[6]=f2bf(v3.z); s1[7]=f2bf(v3.w);
            *(short8*)&Bs[srow * LDK + shalf * 16]     = s0;
            *(short8*)&Bs[srow * LDK + shalf * 16 + 8] = s1;
        }
        __syncthreads();

        short8 af[4], bfr[4];
#pragma unroll
        for (int rt = 0; rt < 4; ++rt)
            af[rt] = *(const short8*)&As[(wrow + rt * 16 + lm) * LDK + lq * 8];
#pragma unroll
        for (int ct = 0; ct < 4; ++ct)
            bfr[ct] = *(const short8*)&Bs[(wcol + ct * 16 + lm) * LDK + lq * 8];
#pragma unroll
        for (int rt = 0; rt < 4; ++rt)
#pragma unroll
            for (int ct = 0; ct < 4; ++ct)
                acc[rt][ct] = __builtin_amdgcn_mfma_f32_16x16x32_bf16(
                    af[rt], bfr[ct], acc[rt][ct], 0, 0, 0);
        __syncthreads();
    }

    // epilogue: D row = lq*4 + r, col = lm
#pragma unroll
    for (int ct = 0; ct < 4; ++ct) {
        int gcol = wcol + ct * 16 + lm;
        float bv = bias[gcol];
#pragma unroll
        for (int rt = 0; rt < 4; ++rt) {
#pragma unroll
            for (int r = 0; r < 4; ++r) {
                int grow = m0 + wrow + rt * 16 + lq * 4 + r;
                if (grow < N_NODES)
                    linbf[(size_t)grow * OUT_CH + gcol] = f2bf(acc[rt][ct][r] + bv);
            }
        }
    }
}

// ---------------- level 1: bucket edges by dst>>7 ------------------------
__global__ __launch_bounds__(256) void bucket_scatter(const int* __restrict__ src,
                                                      const int* __restrict__ dst,
                                                      int* __restrict__ bcnt,
                                                      uint2* __restrict__ rec) {
    __shared__ int  lhist[NB];
    __shared__ int  lscan[NB];
    __shared__ int  lbase[NB];
    __shared__ uint2 staged[L1_CHUNK];   // 16 KB

    const int tid = threadIdx.x;
    const int e0  = blockIdx.x * L1_CHUNK;
    const int total = min(L1_CHUNK, N_EDGES - e0);

    for (int i = tid; i < NB; i += 256) lhist[i] = 0;
    __syncthreads();

    int myd[8], mys[8], myr[8];
#pragma unroll
    for (int j = 0; j < 8; ++j) {
        int i = tid + j * 256;
        myd[j] = -1;
        if (i < total) {
            int d = dst[e0 + i];
            int s = src[e0 + i];
            myd[j] = d; mys[j] = s;
            myr[j] = atomicAdd(&lhist[d >> 7], 1);
        }
    }
    __syncthreads();

    // exclusive scan lhist -> lscan (wave 0, 7 chunks of 64)
    if (tid < 64) {
        int carry = 0;
        for (int c = 0; c < NB; c += 64) {
            int idx = c + tid;
            int v = (idx < NB) ? lhist[idx] : 0;
            int incl = v;
#pragma unroll
            for (int s = 1; s < 64; s <<= 1) {
                int t = __shfl_up(incl, s, 64);
                if (tid >= s) incl += t;
            }
            if (idx < NB) lscan[idx] = carry + incl - v;
            carry += __shfl(incl, 63, 64);
        }
    }
    __syncthreads();

    // reserve global space (one atomic per nonempty bucket) + stage locally
    for (int bkt = tid; bkt < NB; bkt += 256) {
        int c = lhist[bkt];
        lbase[bkt] = c ? atomicAdd(&bcnt[bkt], c) : 0;
    }
#pragma unroll
    for (int j = 0; j < 8; ++j) {
        if (myd[j] >= 0) {
            int b = myd[j] >> 7;
            staged[lscan[b] + myr[j]] = make_uint2((unsigned)mys[j], (unsigned)myd[j]);
        }
    }
    __syncthreads();

    // write out: bucket-grouped runs -> mostly-contiguous global stores
    for (int p = tid; p < total; p += 256) {
        uint2 r = staged[p];
        int b = (int)(r.y >> 7);
        int gpos = lbase[b] + (p - lscan[b]);
        if (gpos < CAP)
            rec[(size_t)b * CAP + gpos] = r;
    }
}

// ---------------- level 2: fine sort within bucket, build CSR ------------
__global__ __launch_bounds__(256) void fine_sort(const int* __restrict__ bcnt,
                                                 const uint2* __restrict__ rec,
                                                 int* __restrict__ srcs,   // aliases rec
                                                 int* __restrict__ off_g,
                                                 int* __restrict__ deg_g) {
    __shared__ int sdst[CAP];    // 12 KB
    __shared__ int ssrc[CAP];    // 12 KB
    __shared__ int fh[128], fo[128], fc[128];

    const int b = blockIdx.x;
    const int tid = threadIdx.x;
    const int cnt = min(bcnt[b], CAP);

    for (int i = tid; i < cnt; i += 256) {
        uint2 r = rec[(size_t)b * CAP + i];
        sdst[i] = (int)(r.y & 127u);
        ssrc[i] = (int)r.x;
    }
    if (tid < 128) fh[tid] = 0;
    __syncthreads();

    for (int i = tid; i < cnt; i += 256) atomicAdd(&fh[sdst[i]], 1);
    __syncthreads();

    if (tid < 64) {
        int carry = 0;
        for (int c = 0; c < 128; c += 64) {
            int v = fh[c + tid];
            int incl = v;
#pragma unroll
            for (int s = 1; s < 64; s <<= 1) {
                int t = __shfl_up(incl, s, 64);
                if (tid >= s) incl += t;
            }
            fo[c + tid] = carry + incl - v;
            carry += __shfl(incl, 63, 64);
        }
    }
    __syncthreads();

    if (tid < 128) {
        int node = b * 128 + tid;
        if (node < N_NODES) {
            off_g[node] = b * (CAP * 2) + fo[tid];   // int index into srcs
            deg_g[node] = fh[tid];
        }
        fc[tid] = fo[tid];
    }
    __syncthreads();

    // all reads of rec done (in LDS) -> safe to overwrite region via srcs
    for (int i = tid; i < cnt; i += 256) {
        int r = atomicAdd(&fc[sdst[i]], 1);
        srcs[(size_t)b * (CAP * 2) + r] = ssrc[i];
    }
}

// ---------------- per-node gather + mean (bf16 lin) ----------------------
__global__ __launch_bounds__(256) void gather_mean(const int* __restrict__ srcs,
                                                   const int* __restrict__ off_g,
                                                   const int* __restrict__ deg_g,
                                                   const short* __restrict__ linbf,
                                                   float* __restrict__ out) {
    int n = blockIdx.x * 16 + (threadIdx.x >> 4);   // 16 nodes / block, 16 lanes / node
    if (n >= N_NODES) return;
    const int l = threadIdx.x & 15;                 // lane handles 8 bf16 = 16 B
    const int beg = off_g[n];
    const int deg = deg_g[n];
    const int end = beg + deg;

    float a[8];
#pragma unroll
    for (int j = 0; j < 8; ++j) a[j] = 0.0f;

    int i = beg;
    for (; i + 1 < end; i += 2) {
        int s0 = srcs[i];
        int s1 = srcs[i + 1];
        uint4 u0 = *(const uint4*)&linbf[(size_t)s0 * OUT_CH + l * 8];
        uint4 u1 = *(const uint4*)&linbf[(size_t)s1 * OUT_CH + l * 8];
        const unsigned* p0 = (const unsigned*)&u0;
        const unsigned* p1 = (const unsigned*)&u1;
#pragma unroll
        for (int j = 0; j < 4; ++j) {
            a[2*j]   += __uint_as_float(p0[j] << 16) + __uint_as_float(p1[j] << 16);
            a[2*j+1] += __uint_as_float(p0[j] & 0xffff0000u) + __uint_as_float(p1[j] & 0xffff0000u);
        }
    }
    if (i < end) {
        int s0 = srcs[i];
        uint4 u0 = *(const uint4*)&linbf[(size_t)s0 * OUT_CH + l * 8];
        const unsigned* p0 = (const unsigned*)&u0;
#pragma unroll
        for (int j = 0; j < 4; ++j) {
            a[2*j]   += __uint_as_float(p0[j] << 16);
            a[2*j+1] += __uint_as_float(p0[j] & 0xffff0000u);
        }
    }
    float inv = 1.0f / (float)(deg > 1 ? deg : 1);
    float4 o0, o1;
    o0.x = a[0]*inv; o0.y = a[1]*inv; o0.z = a[2]*inv; o0.w = a[3]*inv;
    o1.x = a[4]*inv; o1.y = a[5]*inv; o1.z = a[6]*inv; o1.w = a[7]*inv;
    float* op = &out[(size_t)n * OUT_CH + l * 8];
    ((float4*)op)[0] = o0;
    ((float4*)op)[1] = o1;
}

extern "C" void kernel_launch(void* const* d_in, const int* in_sizes, int n_in,
                              void* d_out, int out_size, void* d_ws, size_t ws_size,
                              hipStream_t stream) {
    const float* x  = (const float*)d_in[0];
    const int*   ei = (const int*)d_in[1];     // [2][E]: src then dst
    const float* W  = (const float*)d_in[2];
    const float* b  = (const float*)d_in[3];
    float* out = (float*)d_out;

    const int* src = ei;
    const int* dst = ei + N_EDGES;

    // workspace: linbf 12.8MB | rec/srcs 9.61MB | off 200KB | deg 200KB | bcnt
    char* ws = (char*)d_ws;
    short* linbf = (short*)ws;  ws += ((size_t)N_NODES * OUT_CH * sizeof(short) + 255) & ~255ull;
    uint2* rec   = (uint2*)ws;  ws += ((size_t)NB * CAP * sizeof(uint2) + 255) & ~255ull;
    int*   off_g = (int*)ws;    ws += ((size_t)N_NODES * sizeof(int) + 255) & ~255ull;
    int*   deg_g = (int*)ws;    ws += ((size_t)N_NODES * sizeof(int) + 255) & ~255ull;
    int*   bcnt  = (int*)ws;
    int*   srcs  = (int*)rec;   // fine_sort overwrites rec in place

    hipMemsetAsync(bcnt, 0, (size_t)NB * sizeof(int), stream);

    gemm_mfma<<<(N_NODES + GBM - 1) / GBM, 256, 0, stream>>>(x, W, b, linbf);
    bucket_scatter<<<L1_BLOCKS, 256, 0, stream>>>(src, dst, bcnt, rec);
    fine_sort<<<NB, 256, 0, stream>>>(bcnt, rec, srcs, off_g, deg_g);
    gather_mean<<<(N_NODES + 15) / 16, 256, 0, stream>>>(srcs, off_g, deg_g, linbf, out);
}

// Round 5
// 163.277 us; speedup vs baseline: 9.3864x; 1.0633x over previous
//
#include <hip/hip_runtime.h>

#define N_NODES 50000
#define N_EDGES 800000
#define IN_CH   256
#define OUT_CH  128

#define NB        391          // coarse buckets of 128 nodes: ceil(50000/128)
#define CAP       3072         // record capacity per bucket (mean 2048, sd ~45)
#define L1_CHUNK  2048
#define L1_BLOCKS ((N_EDGES + L1_CHUNK - 1) / L1_CHUNK)   // 391

typedef __attribute__((ext_vector_type(8))) short short8;   // 8 bf16 (4 VGPRs)
typedef __attribute__((ext_vector_type(4))) float f32x4;

__device__ __forceinline__ short f2bf(float f) {
    unsigned u = __float_as_uint(f);
    unsigned r = (u + 0x7fffu + ((u >> 16) & 1u)) >> 16;    // RNE
    return (short)r;
}

// ------------- one-time: W fp32 -> bf16, zero bcnt -----------------------
__global__ __launch_bounds__(256) void convert_w(const float* __restrict__ W,
                                                 short* __restrict__ Wbf,
                                                 int* __restrict__ bcnt) {
    int t = blockIdx.x * 256 + threadIdx.x;       // 4096 threads, 8 floats each
    const float* wp = W + t * 8;
    float4 v0 = ((const float4*)wp)[0];
    float4 v1 = ((const float4*)wp)[1];
    short8 s;
    s[0]=f2bf(v0.x); s[1]=f2bf(v0.y); s[2]=f2bf(v0.z); s[3]=f2bf(v0.w);
    s[4]=f2bf(v1.x); s[5]=f2bf(v1.y); s[6]=f2bf(v1.z); s[7]=f2bf(v1.w);
    *(short8*)&Wbf[t * 8] = s;
    if (t < NB) bcnt[t] = 0;
}

// ---------------- MFMA GEMM: linbf[m][n] = bf16( x[m][:].W[n][:] + b[n] )
#define GBM 128
#define GBK 32
#define LDK 40   // padded row length (bf16 elems); 80B stride keeps 16B align
__global__ __launch_bounds__(256) void gemm_mfma(const float* __restrict__ x,
                                                 const short* __restrict__ Wbf,
                                                 const float* __restrict__ bias,
                                                 short* __restrict__ linbf) {
    __shared__ short As[GBM * LDK];    // A tile: [m][k]
    __shared__ short Bs[OUT_CH * LDK]; // B tile: [n][k]

    const int tid = threadIdx.x;
    const int m0  = blockIdx.x * GBM;
    const int w    = tid >> 6;
    const int lane = tid & 63;
    const int lm   = lane & 15;
    const int lq   = lane >> 4;
    const int wrow = (w >> 1) * 64;
    const int wcol = (w & 1) * 64;

    f32x4 acc[4][4];
#pragma unroll
    for (int i = 0; i < 4; ++i)
#pragma unroll
        for (int j = 0; j < 4; ++j) acc[i][j] = (f32x4)(0.0f);

    const int srow  = tid >> 1;       // staging row (0..127)
    const int shalf = tid & 1;        // which 16-k half

    for (int k0 = 0; k0 < IN_CH; k0 += GBK) {
        // stage A: 128 rows x 32 k, fp32 -> bf16
        {
            float4 v0 = make_float4(0.f,0.f,0.f,0.f), v1 = v0, v2 = v0, v3 = v0;
            if (m0 + srow < N_NODES) {
                const float* xp = x + (size_t)(m0 + srow) * IN_CH + k0 + shalf * 16;
                v0 = ((const float4*)xp)[0];
                v1 = ((const float4*)xp)[1];
                v2 = ((const float4*)xp)[2];
                v3 = ((const float4*)xp)[3];
            }
            short8 s0, s1;
            s0[0]=f2bf(v0.x); s0[1]=f2bf(v0.y); s0[2]=f2bf(v0.z); s0[3]=f2bf(v0.w);
            s0[4]=f2bf(v1.x); s0[5]=f2bf(v1.y); s0[6]=f2bf(v1.z); s0[7]=f2bf(v1.w);
            s1[0]=f2bf(v2.x); s1[1]=f2bf(v2.y); s1[2]=f2bf(v2.z); s1[3]=f2bf(v2.w);
            s1[4]=f2bf(v3.x); s1[5]=f2bf(v3.y); s1[6]=f2bf(v3.z); s1[7]=f2bf(v3.w);
            *(short8*)&As[srow * LDK + shalf * 16]     = s0;
            *(short8*)&As[srow * LDK + shalf * 16 + 8] = s1;
        }
        // stage B: 128 n x 32 k (pre-converted bf16, straight copy)
        {
            const short* wp = Wbf + (size_t)srow * IN_CH + k0 + shalf * 16;
            *(short8*)&Bs[srow * LDK + shalf * 16]     = ((const short8*)wp)[0];
            *(short8*)&Bs[srow * LDK + shalf * 16 + 8] = ((const short8*)wp)[1];
        }
        __syncthreads();

        short8 af[4], bfr[4];
#pragma unroll
        for (int rt = 0; rt < 4; ++rt)
            af[rt] = *(const short8*)&As[(wrow + rt * 16 + lm) * LDK + lq * 8];
#pragma unroll
        for (int ct = 0; ct < 4; ++ct)
            bfr[ct] = *(const short8*)&Bs[(wcol + ct * 16 + lm) * LDK + lq * 8];
#pragma unroll
        for (int rt = 0; rt < 4; ++rt)
#pragma unroll
            for (int ct = 0; ct < 4; ++ct)
                acc[rt][ct] = __builtin_amdgcn_mfma_f32_16x16x32_bf16(
                    af[rt], bfr[ct], acc[rt][ct], 0, 0, 0);
        __syncthreads();
    }

    // epilogue: D row = lq*4 + r, col = lm
#pragma unroll
    for (int ct = 0; ct < 4; ++ct) {
        int gcol = wcol + ct * 16 + lm;
        float bv = bias[gcol];
#pragma unroll
        for (int rt = 0; rt < 4; ++rt) {
#pragma unroll
            for (int r = 0; r < 4; ++r) {
                int grow = m0 + wrow + rt * 16 + lq * 4 + r;
                if (grow < N_NODES)
                    linbf[(size_t)grow * OUT_CH + gcol] = f2bf(acc[rt][ct][r] + bv);
            }
        }
    }
}

// ---------------- level 1: bucket edges by dst>>7 ------------------------
// packed record: src (16b) | (dst&127)<<16 (7b) | (dst>>7)<<23 (9b)
__global__ __launch_bounds__(256) void bucket_scatter(const int* __restrict__ src,
                                                      const int* __restrict__ dst,
                                                      int* __restrict__ bcnt,
                                                      unsigned* __restrict__ rec) {
    __shared__ int lhist[NB];
    __shared__ int lscan[NB];
    __shared__ int lbase[NB];
    __shared__ unsigned staged[L1_CHUNK];   // 8 KB

    const int tid = threadIdx.x;
    const int e0  = blockIdx.x * L1_CHUNK;
    const int total = min(L1_CHUNK, N_EDGES - e0);

    for (int i = tid; i < NB; i += 256) lhist[i] = 0;
    __syncthreads();

    unsigned mypk[8];
    int myr[8];
    int myb[8];
#pragma unroll
    for (int j = 0; j < 8; ++j) {
        int i = tid + j * 256;
        myb[j] = -1;
        if (i < total) {
            unsigned d = (unsigned)dst[e0 + i];
            unsigned s = (unsigned)src[e0 + i];
            int b = (int)(d >> 7);
            myb[j] = b;
            mypk[j] = s | ((d & 127u) << 16) | ((unsigned)b << 23);
            myr[j] = atomicAdd(&lhist[b], 1);
        }
    }
    __syncthreads();

    // exclusive scan lhist -> lscan (wave 0, 7 chunks of 64)
    if (tid < 64) {
        int carry = 0;
        for (int c = 0; c < NB; c += 64) {
            int idx = c + tid;
            int v = (idx < NB) ? lhist[idx] : 0;
            int incl = v;
#pragma unroll
            for (int s = 1; s < 64; s <<= 1) {
                int t = __shfl_up(incl, s, 64);
                if (tid >= s) incl += t;
            }
            if (idx < NB) lscan[idx] = carry + incl - v;
            carry += __shfl(incl, 63, 64);
        }
    }
    __syncthreads();

    // reserve global space (one atomic per nonempty bucket) + stage locally
    for (int bkt = tid; bkt < NB; bkt += 256) {
        int c = lhist[bkt];
        lbase[bkt] = c ? atomicAdd(&bcnt[bkt], c) : 0;
    }
#pragma unroll
    for (int j = 0; j < 8; ++j) {
        if (myb[j] >= 0)
            staged[lscan[myb[j]] + myr[j]] = mypk[j];
    }
    __syncthreads();

    // write out: bucket-grouped runs -> mostly-contiguous global stores
    for (int p = tid; p < total; p += 256) {
        unsigned r = staged[p];
        int b = (int)(r >> 23);
        int gpos = lbase[b] + (p - lscan[b]);
        if (gpos < CAP)
            rec[(size_t)b * CAP + gpos] = r;
    }
}

// ---------------- level 2: fine sort within bucket, build CSR ------------
__global__ __launch_bounds__(256) void fine_sort(const int* __restrict__ bcnt,
                                                 const unsigned* __restrict__ rec,
                                                 unsigned short* __restrict__ srcs,
                                                 int* __restrict__ off_g,
                                                 int* __restrict__ deg_g) {
    __shared__ unsigned srec[CAP];   // 12 KB
    __shared__ int fh[128], fo[128], fc[128];

    const int b = blockIdx.x;
    const int tid = threadIdx.x;
    const int cnt = min(bcnt[b], CAP);

    for (int i = tid; i < cnt; i += 256)
        srec[i] = rec[(size_t)b * CAP + i];
    if (tid < 128) fh[tid] = 0;
    __syncthreads();

    for (int i = tid; i < cnt; i += 256)
        atomicAdd(&fh[(srec[i] >> 16) & 127u], 1);
    __syncthreads();

    if (tid < 64) {
        int carry = 0;
        for (int c = 0; c < 128; c += 64) {
            int v = fh[c + tid];
            int incl = v;
#pragma unroll
            for (int s = 1; s < 64; s <<= 1) {
                int t = __shfl_up(incl, s, 64);
                if (tid >= s) incl += t;
            }
            fo[c + tid] = carry + incl - v;
            carry += __shfl(incl, 63, 64);
        }
    }
    __syncthreads();

    if (tid < 128) {
        int node = b * 128 + tid;
        if (node < N_NODES) {
            off_g[node] = b * CAP + fo[tid];
            deg_g[node] = fh[tid];
        }
        fc[tid] = fo[tid];
    }
    __syncthreads();

    for (int i = tid; i < cnt; i += 256) {
        unsigned r = srec[i];
        int p = atomicAdd(&fc[(r >> 16) & 127u], 1);
        srcs[(size_t)b * CAP + p] = (unsigned short)(r & 0xffffu);
    }
}

// ---------------- per-node gather + mean (bf16 lin) ----------------------
__global__ __launch_bounds__(256) void gather_mean(const unsigned short* __restrict__ srcs,
                                                   const int* __restrict__ off_g,
                                                   const int* __restrict__ deg_g,
                                                   const short* __restrict__ linbf,
                                                   float* __restrict__ out) {
    int n = blockIdx.x * 16 + (threadIdx.x >> 4);   // 16 nodes / block, 16 lanes / node
    if (n >= N_NODES) return;
    const int l = threadIdx.x & 15;                 // lane handles 8 bf16 = 16 B
    const int beg = off_g[n];
    const int deg = deg_g[n];
    const int end = beg + deg;

    float a[8];
#pragma unroll
    for (int j = 0; j < 8; ++j) a[j] = 0.0f;

    int i = beg;
    for (; i + 3 < end; i += 4) {
        uint4 u[4];
#pragma unroll
        for (int e = 0; e < 4; ++e) {
            int s = srcs[i + e];
            u[e] = *(const uint4*)&linbf[(size_t)s * OUT_CH + l * 8];
        }
#pragma unroll
        for (int e = 0; e < 4; ++e) {
            const unsigned* p = (const unsigned*)&u[e];
#pragma unroll
            for (int j = 0; j < 4; ++j) {
                a[2*j]   += __uint_as_float(p[j] << 16);
                a[2*j+1] += __uint_as_float(p[j] & 0xffff0000u);
            }
        }
    }
    for (; i < end; ++i) {
        int s = srcs[i];
        uint4 u0 = *(const uint4*)&linbf[(size_t)s * OUT_CH + l * 8];
        const unsigned* p0 = (const unsigned*)&u0;
#pragma unroll
        for (int j = 0; j < 4; ++j) {
            a[2*j]   += __uint_as_float(p0[j] << 16);
            a[2*j+1] += __uint_as_float(p0[j] & 0xffff0000u);
        }
    }
    float inv = 1.0f / (float)(deg > 1 ? deg : 1);
    float4 o0, o1;
    o0.x = a[0]*inv; o0.y = a[1]*inv; o0.z = a[2]*inv; o0.w = a[3]*inv;
    o1.x = a[4]*inv; o1.y = a[5]*inv; o1.z = a[6]*inv; o1.w = a[7]*inv;
    float* op = &out[(size_t)n * OUT_CH + l * 8];
    ((float4*)op)[0] = o0;
    ((float4*)op)[1] = o1;
}

extern "C" void kernel_launch(void* const* d_in, const int* in_sizes, int n_in,
                              void* d_out, int out_size, void* d_ws, size_t ws_size,
                              hipStream_t stream) {
    const float* x  = (const float*)d_in[0];
    const int*   ei = (const int*)d_in[1];     // [2][E]: src then dst
    const float* W  = (const float*)d_in[2];
    const float* b  = (const float*)d_in[3];
    float* out = (float*)d_out;

    const int* src = ei;
    const int* dst = ei + N_EDGES;

    // workspace: linbf 12.8MB | Wbf 64KB | rec 4.8MB | srcs 2.4MB | off | deg | bcnt
    char* ws = (char*)d_ws;
    short*    linbf = (short*)ws;    ws += ((size_t)N_NODES * OUT_CH * sizeof(short) + 255) & ~255ull;
    short*    Wbf   = (short*)ws;    ws += ((size_t)IN_CH * OUT_CH * sizeof(short) + 255) & ~255ull;
    unsigned* rec   = (unsigned*)ws; ws += ((size_t)NB * CAP * sizeof(unsigned) + 255) & ~255ull;
    unsigned short* srcs = (unsigned short*)ws;
                                     ws += ((size_t)NB * CAP * sizeof(unsigned short) + 255) & ~255ull;
    int* off_g = (int*)ws;           ws += ((size_t)N_NODES * sizeof(int) + 255) & ~255ull;
    int* deg_g = (int*)ws;           ws += ((size_t)N_NODES * sizeof(int) + 255) & ~255ull;
    int* bcnt  = (int*)ws;

    convert_w<<<16, 256, 0, stream>>>(W, Wbf, bcnt);
    gemm_mfma<<<(N_NODES + GBM - 1) / GBM, 256, 0, stream>>>(x, Wbf, b, linbf);
    bucket_scatter<<<L1_BLOCKS, 256, 0, stream>>>(src, dst, bcnt, rec);
    fine_sort<<<NB, 256, 0, stream>>>(bcnt, rec, srcs, off_g, deg_g);
    gather_mean<<<(N_NODES + 15) / 16, 256, 0, stream>>>(srcs, off_g, deg_g, linbf, out);
}

// Round 6
// 156.930 us; speedup vs baseline: 9.7661x; 1.0404x over previous
//
#include <hip/hip_runtime.h>

#define N_NODES 50000
#define N_EDGES 800000
#define IN_CH   256
#define OUT_CH  128

#define NB        391          // coarse buckets of 128 nodes: ceil(50000/128)
#define CAP       3072         // record capacity per bucket (mean 2048, sd ~45)
#define L1_CHUNK  2048
#define NGEMM     ((N_NODES + 127) / 128)                 // 391 gemm blocks

typedef __attribute__((ext_vector_type(8))) short short8;   // 8 bf16 (4 VGPRs)
typedef __attribute__((ext_vector_type(4))) float f32x4;

__device__ __forceinline__ short f2bf(float f) {
    unsigned u = __float_as_uint(f);
    unsigned r = (u + 0x7fffu + ((u >> 16) & 1u)) >> 16;    // RNE
    return (short)r;
}

// ------------- one-time: W fp32 -> bf16, zero bcnt -----------------------
__global__ __launch_bounds__(256) void convert_w(const float* __restrict__ W,
                                                 short* __restrict__ Wbf,
                                                 int* __restrict__ bcnt) {
    int t = blockIdx.x * 256 + threadIdx.x;       // 4096 threads, 8 floats each
    const float* wp = W + t * 8;
    float4 v0 = ((const float4*)wp)[0];
    float4 v1 = ((const float4*)wp)[1];
    short8 s;
    s[0]=f2bf(v0.x); s[1]=f2bf(v0.y); s[2]=f2bf(v0.z); s[3]=f2bf(v0.w);
    s[4]=f2bf(v1.x); s[5]=f2bf(v1.y); s[6]=f2bf(v1.z); s[7]=f2bf(v1.w);
    *(short8*)&Wbf[t * 8] = s;
    if (t < NB) bcnt[t] = 0;
}

// ---------------- fused: MFMA GEMM (blocks 0..390) + edge bucketing ------
#define GBM 128
#define GBK 32
#define LDK 40   // padded row length (bf16 elems); 80B stride keeps 16B align
__global__ __launch_bounds__(256) void gemm_bucket(const float* __restrict__ x,
                                                   const short* __restrict__ Wbf,
                                                   const float* __restrict__ bias,
                                                   short* __restrict__ linbf,
                                                   const int* __restrict__ src,
                                                   const int* __restrict__ dst,
                                                   int* __restrict__ bcnt,
                                                   unsigned* __restrict__ rec) {
    __shared__ __align__(16) char smem[20480];
    const int tid = threadIdx.x;

    if (blockIdx.x < NGEMM) {
        // ================= GEMM part =================
        short* As = (short*)smem;            // 10240 B: [m][k] tile
        short* Bs = (short*)(smem + 10240);  // 10240 B: [n][k] tile

        const int m0  = blockIdx.x * GBM;
        const int w    = tid >> 6;
        const int lane = tid & 63;
        const int lm   = lane & 15;
        const int lq   = lane >> 4;
        const int wrow = (w >> 1) * 64;
        const int wcol = (w & 1) * 64;

        f32x4 acc[4][4];
#pragma unroll
        for (int i = 0; i < 4; ++i)
#pragma unroll
            for (int j = 0; j < 4; ++j) acc[i][j] = (f32x4)(0.0f);

        const int srow  = tid >> 1;       // staging row (0..127)
        const int shalf = tid & 1;        // which 16-k half

        for (int k0 = 0; k0 < IN_CH; k0 += GBK) {
            // stage A: 128 rows x 32 k, fp32 -> bf16
            {
                float4 v0 = make_float4(0.f,0.f,0.f,0.f), v1 = v0, v2 = v0, v3 = v0;
                if (m0 + srow < N_NODES) {
                    const float* xp = x + (size_t)(m0 + srow) * IN_CH + k0 + shalf * 16;
                    v0 = ((const float4*)xp)[0];
                    v1 = ((const float4*)xp)[1];
                    v2 = ((const float4*)xp)[2];
                    v3 = ((const float4*)xp)[3];
                }
                short8 s0, s1;
                s0[0]=f2bf(v0.x); s0[1]=f2bf(v0.y); s0[2]=f2bf(v0.z); s0[3]=f2bf(v0.w);
                s0[4]=f2bf(v1.x); s0[5]=f2bf(v1.y); s0[6]=f2bf(v1.z); s0[7]=f2bf(v1.w);
                s1[0]=f2bf(v2.x); s1[1]=f2bf(v2.y); s1[2]=f2bf(v2.z); s1[3]=f2bf(v2.w);
                s1[4]=f2bf(v3.x); s1[5]=f2bf(v3.y); s1[6]=f2bf(v3.z); s1[7]=f2bf(v3.w);
                *(short8*)&As[srow * LDK + shalf * 16]     = s0;
                *(short8*)&As[srow * LDK + shalf * 16 + 8] = s1;
            }
            // stage B: 128 n x 32 k (pre-converted bf16, straight copy)
            {
                const short* wp = Wbf + (size_t)srow * IN_CH + k0 + shalf * 16;
                *(short8*)&Bs[srow * LDK + shalf * 16]     = ((const short8*)wp)[0];
                *(short8*)&Bs[srow * LDK + shalf * 16 + 8] = ((const short8*)wp)[1];
            }
            __syncthreads();

            short8 af[4], bfr[4];
#pragma unroll
            for (int rt = 0; rt < 4; ++rt)
                af[rt] = *(const short8*)&As[(wrow + rt * 16 + lm) * LDK + lq * 8];
#pragma unroll
            for (int ct = 0; ct < 4; ++ct)
                bfr[ct] = *(const short8*)&Bs[(wcol + ct * 16 + lm) * LDK + lq * 8];
#pragma unroll
            for (int rt = 0; rt < 4; ++rt)
#pragma unroll
                for (int ct = 0; ct < 4; ++ct)
                    acc[rt][ct] = __builtin_amdgcn_mfma_f32_16x16x32_bf16(
                        af[rt], bfr[ct], acc[rt][ct], 0, 0, 0);
            __syncthreads();
        }

        // epilogue: D row = lq*4 + r, col = lm
#pragma unroll
        for (int ct = 0; ct < 4; ++ct) {
            int gcol = wcol + ct * 16 + lm;
            float bv = bias[gcol];
#pragma unroll
            for (int rt = 0; rt < 4; ++rt) {
#pragma unroll
                for (int r = 0; r < 4; ++r) {
                    int grow = m0 + wrow + rt * 16 + lq * 4 + r;
                    if (grow < N_NODES)
                        linbf[(size_t)grow * OUT_CH + gcol] = f2bf(acc[rt][ct][r] + bv);
                }
            }
        }
    } else {
        // ================= bucket-scatter part =================
        // packed record: src (16b) | (dst&127)<<16 (7b) | (dst>>7)<<23 (9b)
        int* lhist       = (int*)smem;             // 1564 B
        int* lscan       = (int*)(smem + 1568);    // 1564 B
        int* lbase       = (int*)(smem + 3136);    // 1564 B
        unsigned* staged = (unsigned*)(smem + 4704); // 8192 B

        const int blk = blockIdx.x - NGEMM;
        const int e0  = blk * L1_CHUNK;
        const int total = min(L1_CHUNK, N_EDGES - e0);

        for (int i = tid; i < NB; i += 256) lhist[i] = 0;
        __syncthreads();

        unsigned mypk[8];
        int myr[8];
        int myb[8];
#pragma unroll
        for (int j = 0; j < 8; ++j) {
            int i = tid + j * 256;
            myb[j] = -1;
            if (i < total) {
                unsigned d = (unsigned)dst[e0 + i];
                unsigned s = (unsigned)src[e0 + i];
                int b = (int)(d >> 7);
                myb[j] = b;
                mypk[j] = s | ((d & 127u) << 16) | ((unsigned)b << 23);
                myr[j] = atomicAdd(&lhist[b], 1);
            }
        }
        __syncthreads();

        // exclusive scan lhist -> lscan (wave 0, 7 chunks of 64)
        if (tid < 64) {
            int carry = 0;
            for (int c = 0; c < NB; c += 64) {
                int idx = c + tid;
                int v = (idx < NB) ? lhist[idx] : 0;
                int incl = v;
#pragma unroll
                for (int s = 1; s < 64; s <<= 1) {
                    int t = __shfl_up(incl, s, 64);
                    if (tid >= s) incl += t;
                }
                if (idx < NB) lscan[idx] = carry + incl - v;
                carry += __shfl(incl, 63, 64);
            }
        }
        __syncthreads();

        // reserve global space (one atomic per nonempty bucket) + stage locally
        for (int bkt = tid; bkt < NB; bkt += 256) {
            int c = lhist[bkt];
            lbase[bkt] = c ? atomicAdd(&bcnt[bkt], c) : 0;
        }
#pragma unroll
        for (int j = 0; j < 8; ++j) {
            if (myb[j] >= 0)
                staged[lscan[myb[j]] + myr[j]] = mypk[j];
        }
        __syncthreads();

        // write out: bucket-grouped runs -> mostly-contiguous global stores
        for (int p = tid; p < total; p += 256) {
            unsigned r = staged[p];
            int b = (int)(r >> 23);
            int gpos = lbase[b] + (p - lscan[b]);
            if (gpos < CAP)
                rec[(size_t)b * CAP + gpos] = r;
        }
    }
}

// ---------- fused: fine sort (LDS) + gather-mean for 128 nodes/block -----
__global__ __launch_bounds__(256) void fine_gather(const int* __restrict__ bcnt,
                                                   const unsigned* __restrict__ rec,
                                                   const short* __restrict__ linbf,
                                                   float* __restrict__ out) {
    __shared__ unsigned srec[CAP];          // 12288 B
    __shared__ unsigned short ssrc[CAP];    // 6144 B
    __shared__ int fh[128], fo[128], fc[128];

    const int b = blockIdx.x;
    const int tid = threadIdx.x;
    const int cnt = min(bcnt[b], CAP);

    // load records, histogram fine node (dst & 127)
    for (int i = tid; i < cnt; i += 256)
        srec[i] = rec[(size_t)b * CAP + i];
    if (tid < 128) fh[tid] = 0;
    __syncthreads();

    for (int i = tid; i < cnt; i += 256)
        atomicAdd(&fh[(srec[i] >> 16) & 127u], 1);
    __syncthreads();

    // exclusive scan of 128 counters (wave 0)
    if (tid < 64) {
        int carry = 0;
        for (int c = 0; c < 128; c += 64) {
            int v = fh[c + tid];
            int incl = v;
#pragma unroll
            for (int s = 1; s < 64; s <<= 1) {
                int t = __shfl_up(incl, s, 64);
                if (tid >= s) incl += t;
            }
            fo[c + tid] = carry + incl - v;
            carry += __shfl(incl, 63, 64);
        }
    }
    __syncthreads();
    if (tid < 128) fc[tid] = fo[tid];
    __syncthreads();

    // sorted scatter into LDS ssrc
    for (int i = tid; i < cnt; i += 256) {
        unsigned r = srec[i];
        int p = atomicAdd(&fc[(r >> 16) & 127u], 1);
        ssrc[p] = (unsigned short)(r & 0xffffu);
    }
    __syncthreads();

    // gather phase: 16 lanes per node, 16 nodes in flight, 8 rounds
    const int l = tid & 15;
#pragma unroll 1
    for (int g = 0; g < 8; ++g) {
        int nl = g * 16 + (tid >> 4);          // local node 0..127
        int n = b * 128 + nl;
        if (n >= N_NODES) continue;
        const int beg = fo[nl];
        const int deg = fh[nl];
        const int end = beg + deg;

        float a[8];
#pragma unroll
        for (int j = 0; j < 8; ++j) a[j] = 0.0f;

        int i = beg;
        for (; i + 3 < end; i += 4) {
            uint4 u[4];
#pragma unroll
            for (int e = 0; e < 4; ++e) {
                int s = ssrc[i + e];
                u[e] = *(const uint4*)&linbf[(size_t)s * OUT_CH + l * 8];
            }
#pragma unroll
            for (int e = 0; e < 4; ++e) {
                const unsigned* p = (const unsigned*)&u[e];
#pragma unroll
                for (int j = 0; j < 4; ++j) {
                    a[2*j]   += __uint_as_float(p[j] << 16);
                    a[2*j+1] += __uint_as_float(p[j] & 0xffff0000u);
                }
            }
        }
        for (; i < end; ++i) {
            int s = ssrc[i];
            uint4 u0 = *(const uint4*)&linbf[(size_t)s * OUT_CH + l * 8];
            const unsigned* p0 = (const unsigned*)&u0;
#pragma unroll
            for (int j = 0; j < 4; ++j) {
                a[2*j]   += __uint_as_float(p0[j] << 16);
                a[2*j+1] += __uint_as_float(p0[j] & 0xffff0000u);
            }
        }
        float inv = 1.0f / (float)(deg > 1 ? deg : 1);
        float4 o0, o1;
        o0.x = a[0]*inv; o0.y = a[1]*inv; o0.z = a[2]*inv; o0.w = a[3]*inv;
        o1.x = a[4]*inv; o1.y = a[5]*inv; o1.z = a[6]*inv; o1.w = a[7]*inv;
        float* op = &out[(size_t)n * OUT_CH + l * 8];
        ((float4*)op)[0] = o0;
        ((float4*)op)[1] = o1;
    }
}

extern "C" void kernel_launch(void* const* d_in, const int* in_sizes, int n_in,
                              void* d_out, int out_size, void* d_ws, size_t ws_size,
                              hipStream_t stream) {
    const float* x  = (const float*)d_in[0];
    const int*   ei = (const int*)d_in[1];     // [2][E]: src then dst
    const float* W  = (const float*)d_in[2];
    const float* b  = (const float*)d_in[3];
    float* out = (float*)d_out;

    const int* src = ei;
    const int* dst = ei + N_EDGES;

    // workspace: linbf 12.8MB | Wbf 64KB | rec 4.8MB | bcnt
    char* ws = (char*)d_ws;
    short*    linbf = (short*)ws;    ws += ((size_t)N_NODES * OUT_CH * sizeof(short) + 255) & ~255ull;
    short*    Wbf   = (short*)ws;    ws += ((size_t)IN_CH * OUT_CH * sizeof(short) + 255) & ~255ull;
    unsigned* rec   = (unsigned*)ws; ws += ((size_t)NB * CAP * sizeof(unsigned) + 255) & ~255ull;
    int*      bcnt  = (int*)ws;

    convert_w<<<16, 256, 0, stream>>>(W, Wbf, bcnt);
    gemm_bucket<<<NGEMM + NB, 256, 0, stream>>>(x, Wbf, b, linbf, src, dst, bcnt, rec);
    fine_gather<<<NB, 256, 0, stream>>>(bcnt, rec, linbf, out);
}

// Round 7
// 148.149 us; speedup vs baseline: 10.3449x; 1.0593x over previous
//
#include <hip/hip_runtime.h>

#define N_NODES 50000
#define N_EDGES 800000
#define IN_CH   256
#define OUT_CH  128

#define NB        391          // coarse buckets of 128 nodes: ceil(50000/128)
#define CAP       3072         // record capacity per bucket (mean 2048, sd ~45)
#define L1_CHUNK  2048
#define NGEMM     ((N_NODES + 127) / 128)                 // 391 gemm blocks

typedef __attribute__((ext_vector_type(8))) short short8;   // 8 bf16 (4 VGPRs)
typedef __attribute__((ext_vector_type(4))) float f32x4;

__device__ __forceinline__ short f2bf(float f) {
    unsigned u = __float_as_uint(f);
    unsigned r = (u + 0x7fffu + ((u >> 16) & 1u)) >> 16;    // RNE
    return (short)r;
}

// ------------- one-time: W fp32 -> bf16, zero bcnt -----------------------
__global__ __launch_bounds__(256) void convert_w(const float* __restrict__ W,
                                                 short* __restrict__ Wbf,
                                                 int* __restrict__ bcnt) {
    int t = blockIdx.x * 256 + threadIdx.x;       // 4096 threads, 8 floats each
    const float* wp = W + t * 8;
    float4 v0 = ((const float4*)wp)[0];
    float4 v1 = ((const float4*)wp)[1];
    short8 s;
    s[0]=f2bf(v0.x); s[1]=f2bf(v0.y); s[2]=f2bf(v0.z); s[3]=f2bf(v0.w);
    s[4]=f2bf(v1.x); s[5]=f2bf(v1.y); s[6]=f2bf(v1.z); s[7]=f2bf(v1.w);
    *(short8*)&Wbf[t * 8] = s;
    if (t < NB) bcnt[t] = 0;
}

// ---------------- fused: MFMA GEMM (blocks 0..390) + edge bucketing ------
#define GBM 128
#define GBK 32
#define LDK 40   // padded row length (bf16 elems); 80B stride keeps 16B align
__global__ __launch_bounds__(256) void gemm_bucket(const float* __restrict__ x,
                                                   const short* __restrict__ Wbf,
                                                   const float* __restrict__ bias,
                                                   short* __restrict__ linbf,
                                                   const int* __restrict__ src,
                                                   const int* __restrict__ dst,
                                                   int* __restrict__ bcnt,
                                                   unsigned* __restrict__ rec) {
    __shared__ __align__(16) char smem[20480];
    const int tid = threadIdx.x;

    if (blockIdx.x < NGEMM) {
        // ================= GEMM part =================
        short* As = (short*)smem;            // 10240 B: [m][k] tile
        short* Bs = (short*)(smem + 10240);  // 10240 B: [n][k] tile

        const int m0  = blockIdx.x * GBM;
        const int w    = tid >> 6;
        const int lane = tid & 63;
        const int lm   = lane & 15;
        const int lq   = lane >> 4;
        const int wrow = (w >> 1) * 64;
        const int wcol = (w & 1) * 64;

        f32x4 acc[4][4];
#pragma unroll
        for (int i = 0; i < 4; ++i)
#pragma unroll
            for (int j = 0; j < 4; ++j) acc[i][j] = (f32x4)(0.0f);

        const int srow  = tid >> 1;       // staging row (0..127)
        const int shalf = tid & 1;        // which 16-k half

        for (int k0 = 0; k0 < IN_CH; k0 += GBK) {
            // stage A: 128 rows x 32 k, fp32 -> bf16
            {
                float4 v0 = make_float4(0.f,0.f,0.f,0.f), v1 = v0, v2 = v0, v3 = v0;
                if (m0 + srow < N_NODES) {
                    const float* xp = x + (size_t)(m0 + srow) * IN_CH + k0 + shalf * 16;
                    v0 = ((const float4*)xp)[0];
                    v1 = ((const float4*)xp)[1];
                    v2 = ((const float4*)xp)[2];
                    v3 = ((const float4*)xp)[3];
                }
                short8 s0, s1;
                s0[0]=f2bf(v0.x); s0[1]=f2bf(v0.y); s0[2]=f2bf(v0.z); s0[3]=f2bf(v0.w);
                s0[4]=f2bf(v1.x); s0[5]=f2bf(v1.y); s0[6]=f2bf(v1.z); s0[7]=f2bf(v1.w);
                s1[0]=f2bf(v2.x); s1[1]=f2bf(v2.y); s1[2]=f2bf(v2.z); s1[3]=f2bf(v2.w);
                s1[4]=f2bf(v3.x); s1[5]=f2bf(v3.y); s1[6]=f2bf(v3.z); s1[7]=f2bf(v3.w);
                *(short8*)&As[srow * LDK + shalf * 16]     = s0;
                *(short8*)&As[srow * LDK + shalf * 16 + 8] = s1;
            }
            // stage B: 128 n x 32 k (pre-converted bf16, straight copy)
            {
                const short* wp = Wbf + (size_t)srow * IN_CH + k0 + shalf * 16;
                *(short8*)&Bs[srow * LDK + shalf * 16]     = ((const short8*)wp)[0];
                *(short8*)&Bs[srow * LDK + shalf * 16 + 8] = ((const short8*)wp)[1];
            }
            __syncthreads();

            short8 af[4], bfr[4];
#pragma unroll
            for (int rt = 0; rt < 4; ++rt)
                af[rt] = *(const short8*)&As[(wrow + rt * 16 + lm) * LDK + lq * 8];
#pragma unroll
            for (int ct = 0; ct < 4; ++ct)
                bfr[ct] = *(const short8*)&Bs[(wcol + ct * 16 + lm) * LDK + lq * 8];
#pragma unroll
            for (int rt = 0; rt < 4; ++rt)
#pragma unroll
                for (int ct = 0; ct < 4; ++ct)
                    acc[rt][ct] = __builtin_amdgcn_mfma_f32_16x16x32_bf16(
                        af[rt], bfr[ct], acc[rt][ct], 0, 0, 0);
            __syncthreads();
        }

        // epilogue: D row = lq*4 + r, col = lm
#pragma unroll
        for (int ct = 0; ct < 4; ++ct) {
            int gcol = wcol + ct * 16 + lm;
            float bv = bias[gcol];
#pragma unroll
            for (int rt = 0; rt < 4; ++rt) {
#pragma unroll
                for (int r = 0; r < 4; ++r) {
                    int grow = m0 + wrow + rt * 16 + lq * 4 + r;
                    if (grow < N_NODES)
                        linbf[(size_t)grow * OUT_CH + gcol] = f2bf(acc[rt][ct][r] + bv);
                }
            }
        }
    } else {
        // ================= bucket-scatter part =================
        // packed record: src (16b) | (dst&127)<<16 (7b) | (dst>>7)<<23 (9b)
        int* lhist       = (int*)smem;             // 1564 B
        int* lscan       = (int*)(smem + 1568);    // 1564 B
        int* lbase       = (int*)(smem + 3136);    // 1564 B
        unsigned* staged = (unsigned*)(smem + 4704); // 8192 B

        const int blk = blockIdx.x - NGEMM;
        const int e0  = blk * L1_CHUNK;
        const int total = min(L1_CHUNK, N_EDGES - e0);

        for (int i = tid; i < NB; i += 256) lhist[i] = 0;
        __syncthreads();

        unsigned mypk[8];
        int myr[8];
        int myb[8];
#pragma unroll
        for (int j = 0; j < 8; ++j) {
            int i = tid + j * 256;
            myb[j] = -1;
            if (i < total) {
                unsigned d = (unsigned)dst[e0 + i];
                unsigned s = (unsigned)src[e0 + i];
                int b = (int)(d >> 7);
                myb[j] = b;
                mypk[j] = s | ((d & 127u) << 16) | ((unsigned)b << 23);
                myr[j] = atomicAdd(&lhist[b], 1);
            }
        }
        __syncthreads();

        // exclusive scan lhist -> lscan (wave 0, 7 chunks of 64)
        if (tid < 64) {
            int carry = 0;
            for (int c = 0; c < NB; c += 64) {
                int idx = c + tid;
                int v = (idx < NB) ? lhist[idx] : 0;
                int incl = v;
#pragma unroll
                for (int s = 1; s < 64; s <<= 1) {
                    int t = __shfl_up(incl, s, 64);
                    if (tid >= s) incl += t;
                }
                if (idx < NB) lscan[idx] = carry + incl - v;
                carry += __shfl(incl, 63, 64);
            }
        }
        __syncthreads();

        // reserve global space (one atomic per nonempty bucket) + stage locally
        for (int bkt = tid; bkt < NB; bkt += 256) {
            int c = lhist[bkt];
            lbase[bkt] = c ? atomicAdd(&bcnt[bkt], c) : 0;
        }
#pragma unroll
        for (int j = 0; j < 8; ++j) {
            if (myb[j] >= 0)
                staged[lscan[myb[j]] + myr[j]] = mypk[j];
        }
        __syncthreads();

        // write out: bucket-grouped runs -> mostly-contiguous global stores
        for (int p = tid; p < total; p += 256) {
            unsigned r = staged[p];
            int b = (int)(r >> 23);
            int gpos = lbase[b] + (p - lscan[b]);
            if (gpos < CAP)
                rec[(size_t)b * CAP + gpos] = r;
        }
    }
}

// ---------- fused: fine sort (LDS) + gather-mean for 128 nodes/block -----
// 512 threads: 8 waves/block for latency hiding on the random-row gather.
#define FG_THR 512
__global__ __launch_bounds__(FG_THR) void fine_gather(const int* __restrict__ bcnt,
                                                      const unsigned* __restrict__ rec,
                                                      const short* __restrict__ linbf,
                                                      float* __restrict__ out) {
    __shared__ unsigned srec[CAP];          // 12288 B
    __shared__ unsigned short ssrc[CAP];    // 6144 B
    __shared__ int fh[128], fo[128], fc[128];

    const int b = blockIdx.x;
    const int tid = threadIdx.x;
    const int cnt = min(bcnt[b], CAP);

    // load records, histogram fine node (dst & 127)
    for (int i = tid; i < cnt; i += FG_THR)
        srec[i] = rec[(size_t)b * CAP + i];
    if (tid < 128) fh[tid] = 0;
    __syncthreads();

    for (int i = tid; i < cnt; i += FG_THR)
        atomicAdd(&fh[(srec[i] >> 16) & 127u], 1);
    __syncthreads();

    // exclusive scan of 128 counters (wave 0)
    if (tid < 64) {
        int carry = 0;
        for (int c = 0; c < 128; c += 64) {
            int v = fh[c + tid];
            int incl = v;
#pragma unroll
            for (int s = 1; s < 64; s <<= 1) {
                int t = __shfl_up(incl, s, 64);
                if (tid >= s) incl += t;
            }
            fo[c + tid] = carry + incl - v;
            carry += __shfl(incl, 63, 64);
        }
    }
    __syncthreads();
    if (tid < 128) fc[tid] = fo[tid];
    __syncthreads();

    // sorted scatter into LDS ssrc
    for (int i = tid; i < cnt; i += FG_THR) {
        unsigned r = srec[i];
        int p = atomicAdd(&fc[(r >> 16) & 127u], 1);
        ssrc[p] = (unsigned short)(r & 0xffffu);
    }
    __syncthreads();

    // gather phase: 16 lanes per node, 32 nodes in flight, 4 rounds
    const int l = tid & 15;
#pragma unroll 1
    for (int g = 0; g < 4; ++g) {
        int nl = g * 32 + (tid >> 4);          // local node 0..127
        int n = b * 128 + nl;
        if (n >= N_NODES) continue;
        const int beg = fo[nl];
        const int deg = fh[nl];
        const int end = beg + deg;

        float a[8];
#pragma unroll
        for (int j = 0; j < 8; ++j) a[j] = 0.0f;

        int i = beg;
        for (; i + 3 < end; i += 4) {
            uint4 u[4];
#pragma unroll
            for (int e = 0; e < 4; ++e) {
                int s = ssrc[i + e];
                u[e] = *(const uint4*)&linbf[(size_t)s * OUT_CH + l * 8];
            }
#pragma unroll
            for (int e = 0; e < 4; ++e) {
                const unsigned* p = (const unsigned*)&u[e];
#pragma unroll
                for (int j = 0; j < 4; ++j) {
                    a[2*j]   += __uint_as_float(p[j] << 16);
                    a[2*j+1] += __uint_as_float(p[j] & 0xffff0000u);
                }
            }
        }
        for (; i < end; ++i) {
            int s = ssrc[i];
            uint4 u0 = *(const uint4*)&linbf[(size_t)s * OUT_CH + l * 8];
            const unsigned* p0 = (const unsigned*)&u0;
#pragma unroll
            for (int j = 0; j < 4; ++j) {
                a[2*j]   += __uint_as_float(p0[j] << 16);
                a[2*j+1] += __uint_as_float(p0[j] & 0xffff0000u);
            }
        }
        float inv = 1.0f / (float)(deg > 1 ? deg : 1);
        float4 o0, o1;
        o0.x = a[0]*inv; o0.y = a[1]*inv; o0.z = a[2]*inv; o0.w = a[3]*inv;
        o1.x = a[4]*inv; o1.y = a[5]*inv; o1.z = a[6]*inv; o1.w = a[7]*inv;
        float* op = &out[(size_t)n * OUT_CH + l * 8];
        ((float4*)op)[0] = o0;
        ((float4*)op)[1] = o1;
    }
}

extern "C" void kernel_launch(void* const* d_in, const int* in_sizes, int n_in,
                              void* d_out, int out_size, void* d_ws, size_t ws_size,
                              hipStream_t stream) {
    const float* x  = (const float*)d_in[0];
    const int*   ei = (const int*)d_in[1];     // [2][E]: src then dst
    const float* W  = (const float*)d_in[2];
    const float* b  = (const float*)d_in[3];
    float* out = (float*)d_out;

    const int* src = ei;
    const int* dst = ei + N_EDGES;

    // workspace: linbf 12.8MB | Wbf 64KB | rec 4.8MB | bcnt
    char* ws = (char*)d_ws;
    short*    linbf = (short*)ws;    ws += ((size_t)N_NODES * OUT_CH * sizeof(short) + 255) & ~255ull;
    short*    Wbf   = (short*)ws;    ws += ((size_t)IN_CH * OUT_CH * sizeof(short) + 255) & ~255ull;
    unsigned* rec   = (unsigned*)ws; ws += ((size_t)NB * CAP * sizeof(unsigned) + 255) & ~255ull;
    int*      bcnt  = (int*)ws;

    convert_w<<<16, 256, 0, stream>>>(W, Wbf, bcnt);
    gemm_bucket<<<NGEMM + NB, 256, 0, stream>>>(x, Wbf, b, linbf, src, dst, bcnt, rec);
    fine_gather<<<NB, FG_THR, 0, stream>>>(bcnt, rec, linbf, out);
}

// Round 8
// 140.151 us; speedup vs baseline: 10.9353x; 1.0571x over previous
//
#include <hip/hip_runtime.h>

#define N_NODES 50000
#define N_EDGES 800000
#define IN_CH   256
#define OUT_CH  128

#define NB        391          // coarse buckets of 128 nodes: ceil(50000/128)
#define CAP       3072         // record capacity per bucket (mean 2048, sd ~45)
#define L1_CHUNK  2048
#define GBM       64
#define NGEMM     ((N_NODES + GBM - 1) / GBM)             // 782 gemm blocks

typedef __attribute__((ext_vector_type(8))) short short8;   // 8 bf16 (4 VGPRs)
typedef __attribute__((ext_vector_type(4))) float f32x4;

__device__ __forceinline__ short f2bf(float f) {
    unsigned u = __float_as_uint(f);
    unsigned r = (u + 0x7fffu + ((u >> 16) & 1u)) >> 16;    // RNE
    return (short)r;
}

// ------------- one-time: W fp32 -> bf16, zero bcnt -----------------------
__global__ __launch_bounds__(256) void convert_w(const float* __restrict__ W,
                                                 short* __restrict__ Wbf,
                                                 int* __restrict__ bcnt) {
    int t = blockIdx.x * 256 + threadIdx.x;       // 4096 threads, 8 floats each
    const float* wp = W + t * 8;
    float4 v0 = ((const float4*)wp)[0];
    float4 v1 = ((const float4*)wp)[1];
    short8 s;
    s[0]=f2bf(v0.x); s[1]=f2bf(v0.y); s[2]=f2bf(v0.z); s[3]=f2bf(v0.w);
    s[4]=f2bf(v1.x); s[5]=f2bf(v1.y); s[6]=f2bf(v1.z); s[7]=f2bf(v1.w);
    *(short8*)&Wbf[t * 8] = s;
    if (t < NB) bcnt[t] = 0;
}

// ---------------- fused: MFMA GEMM (blocks 0..781) + edge bucketing ------
// GEMM tile 64x128: 782 blocks -> ~4.6 blocks/CU so the per-iter HBM
// A-load latency hides across blocks (128-tile gave only 1.5 blocks/CU).
#define GBK 32
#define LDK 40   // padded row length (bf16 elems); 80B stride keeps 16B align
__global__ __launch_bounds__(256) void gemm_bucket(const float* __restrict__ x,
                                                   const short* __restrict__ Wbf,
                                                   const float* __restrict__ bias,
                                                   short* __restrict__ linbf,
                                                   const int* __restrict__ src,
                                                   const int* __restrict__ dst,
                                                   int* __restrict__ bcnt,
                                                   unsigned* __restrict__ rec) {
    __shared__ __align__(16) char smem[15360];
    const int tid = threadIdx.x;

    if (blockIdx.x < NGEMM) {
        // ================= GEMM part =================
        short* As = (short*)smem;            // 5120 B:  [m][k] tile (64 x 32)
        short* Bs = (short*)(smem + 5120);   // 10240 B: [n][k] tile (128 x 32)

        const int m0  = blockIdx.x * GBM;
        const int w    = tid >> 6;
        const int lane = tid & 63;
        const int lm   = lane & 15;
        const int lq   = lane >> 4;
        const int wrow = (w >> 1) * 32;
        const int wcol = (w & 1) * 64;

        f32x4 acc[2][4];
#pragma unroll
        for (int i = 0; i < 2; ++i)
#pragma unroll
            for (int j = 0; j < 4; ++j) acc[i][j] = (f32x4)(0.0f);

        const int arow = tid >> 2;        // A staging row (0..63)
        const int aq   = tid & 3;         // which 8-k group
        const int brow = tid >> 1;        // B staging row (0..127)
        const int bhalf = tid & 1;        // which 16-k half

        for (int k0 = 0; k0 < IN_CH; k0 += GBK) {
            // stage A: 64 rows x 32 k, fp32 -> bf16 (32 B / thread)
            {
                float4 v0 = make_float4(0.f,0.f,0.f,0.f), v1 = v0;
                if (m0 + arow < N_NODES) {
                    const float* xp = x + (size_t)(m0 + arow) * IN_CH + k0 + aq * 8;
                    v0 = ((const float4*)xp)[0];
                    v1 = ((const float4*)xp)[1];
                }
                short8 s;
                s[0]=f2bf(v0.x); s[1]=f2bf(v0.y); s[2]=f2bf(v0.z); s[3]=f2bf(v0.w);
                s[4]=f2bf(v1.x); s[5]=f2bf(v1.y); s[6]=f2bf(v1.z); s[7]=f2bf(v1.w);
                *(short8*)&As[arow * LDK + aq * 8] = s;
            }
            // stage B: 128 n x 32 k (pre-converted bf16, straight copy)
            {
                const short* wp = Wbf + (size_t)brow * IN_CH + k0 + bhalf * 16;
                *(short8*)&Bs[brow * LDK + bhalf * 16]     = ((const short8*)wp)[0];
                *(short8*)&Bs[brow * LDK + bhalf * 16 + 8] = ((const short8*)wp)[1];
            }
            __syncthreads();

            short8 af[2], bfr[4];
#pragma unroll
            for (int rt = 0; rt < 2; ++rt)
                af[rt] = *(const short8*)&As[(wrow + rt * 16 + lm) * LDK + lq * 8];
#pragma unroll
            for (int ct = 0; ct < 4; ++ct)
                bfr[ct] = *(const short8*)&Bs[(wcol + ct * 16 + lm) * LDK + lq * 8];
#pragma unroll
            for (int rt = 0; rt < 2; ++rt)
#pragma unroll
                for (int ct = 0; ct < 4; ++ct)
                    acc[rt][ct] = __builtin_amdgcn_mfma_f32_16x16x32_bf16(
                        af[rt], bfr[ct], acc[rt][ct], 0, 0, 0);
            __syncthreads();
        }

        // epilogue: D row = lq*4 + r, col = lm
#pragma unroll
        for (int ct = 0; ct < 4; ++ct) {
            int gcol = wcol + ct * 16 + lm;
            float bv = bias[gcol];
#pragma unroll
            for (int rt = 0; rt < 2; ++rt) {
#pragma unroll
                for (int r = 0; r < 4; ++r) {
                    int grow = m0 + wrow + rt * 16 + lq * 4 + r;
                    if (grow < N_NODES)
                        linbf[(size_t)grow * OUT_CH + gcol] = f2bf(acc[rt][ct][r] + bv);
                }
            }
        }
    } else {
        // ================= bucket-scatter part =================
        // packed record: src (16b) | (dst&127)<<16 (7b) | (dst>>7)<<23 (9b)
        int* lhist       = (int*)smem;             // 1564 B
        int* lscan       = (int*)(smem + 1568);    // 1564 B
        int* lbase       = (int*)(smem + 3136);    // 1564 B
        unsigned* staged = (unsigned*)(smem + 4704); // 8192 B

        const int blk = blockIdx.x - NGEMM;
        const int e0  = blk * L1_CHUNK;
        const int total = min(L1_CHUNK, N_EDGES - e0);

        for (int i = tid; i < NB; i += 256) lhist[i] = 0;
        __syncthreads();

        unsigned mypk[8];
        int myr[8];
        int myb[8];
#pragma unroll
        for (int j = 0; j < 8; ++j) {
            int i = tid + j * 256;
            myb[j] = -1;
            if (i < total) {
                unsigned d = (unsigned)dst[e0 + i];
                unsigned s = (unsigned)src[e0 + i];
                int b = (int)(d >> 7);
                myb[j] = b;
                mypk[j] = s | ((d & 127u) << 16) | ((unsigned)b << 23);
                myr[j] = atomicAdd(&lhist[b], 1);
            }
        }
        __syncthreads();

        // exclusive scan lhist -> lscan (wave 0, 7 chunks of 64)
        if (tid < 64) {
            int carry = 0;
            for (int c = 0; c < NB; c += 64) {
                int idx = c + tid;
                int v = (idx < NB) ? lhist[idx] : 0;
                int incl = v;
#pragma unroll
                for (int s = 1; s < 64; s <<= 1) {
                    int t = __shfl_up(incl, s, 64);
                    if (tid >= s) incl += t;
                }
                if (idx < NB) lscan[idx] = carry + incl - v;
                carry += __shfl(incl, 63, 64);
            }
        }
        __syncthreads();

        // reserve global space (one atomic per nonempty bucket) + stage locally
        for (int bkt = tid; bkt < NB; bkt += 256) {
            int c = lhist[bkt];
            lbase[bkt] = c ? atomicAdd(&bcnt[bkt], c) : 0;
        }
#pragma unroll
        for (int j = 0; j < 8; ++j) {
            if (myb[j] >= 0)
                staged[lscan[myb[j]] + myr[j]] = mypk[j];
        }
        __syncthreads();

        // write out: bucket-grouped runs -> mostly-contiguous global stores
        for (int p = tid; p < total; p += 256) {
            unsigned r = staged[p];
            int b = (int)(r >> 23);
            int gpos = lbase[b] + (p - lscan[b]);
            if (gpos < CAP)
                rec[(size_t)b * CAP + gpos] = r;
        }
    }
}

// ---------- fused: fine sort (LDS) + gather-mean for 128 nodes/block -----
// 1024 threads: 16 waves/block for latency hiding on the random-row gather.
#define FG_THR 1024
__global__ __launch_bounds__(FG_THR) void fine_gather(const int* __restrict__ bcnt,
                                                      const unsigned* __restrict__ rec,
                                                      const short* __restrict__ linbf,
                                                      float* __restrict__ out) {
    __shared__ unsigned srec[CAP];          // 12288 B
    __shared__ unsigned short ssrc[CAP];    // 6144 B
    __shared__ int fh[128], fo[128], fc[128];

    const int b = blockIdx.x;
    const int tid = threadIdx.x;
    const int cnt = min(bcnt[b], CAP);

    // load records, histogram fine node (dst & 127)
    for (int i = tid; i < cnt; i += FG_THR)
        srec[i] = rec[(size_t)b * CAP + i];
    if (tid < 128) fh[tid] = 0;
    __syncthreads();

    for (int i = tid; i < cnt; i += FG_THR)
        atomicAdd(&fh[(srec[i] >> 16) & 127u], 1);
    __syncthreads();

    // exclusive scan of 128 counters (wave 0)
    if (tid < 64) {
        int carry = 0;
        for (int c = 0; c < 128; c += 64) {
            int v = fh[c + tid];
            int incl = v;
#pragma unroll
            for (int s = 1; s < 64; s <<= 1) {
                int t = __shfl_up(incl, s, 64);
                if (tid >= s) incl += t;
            }
            fo[c + tid] = carry + incl - v;
            carry += __shfl(incl, 63, 64);
        }
    }
    __syncthreads();
    if (tid < 128) fc[tid] = fo[tid];
    __syncthreads();

    // sorted scatter into LDS ssrc
    for (int i = tid; i < cnt; i += FG_THR) {
        unsigned r = srec[i];
        int p = atomicAdd(&fc[(r >> 16) & 127u], 1);
        ssrc[p] = (unsigned short)(r & 0xffffu);
    }
    __syncthreads();

    // gather phase: 16 lanes per node, 64 nodes in flight, 2 rounds
    const int l = tid & 15;
#pragma unroll 1
    for (int g = 0; g < 2; ++g) {
        int nl = g * 64 + (tid >> 4);          // local node 0..127
        int n = b * 128 + nl;
        if (n >= N_NODES) continue;
        const int beg = fo[nl];
        const int deg = fh[nl];
        const int end = beg + deg;

        float a[8];
#pragma unroll
        for (int j = 0; j < 8; ++j) a[j] = 0.0f;

        int i = beg;
        for (; i + 3 < end; i += 4) {
            uint4 u[4];
#pragma unroll
            for (int e = 0; e < 4; ++e) {
                int s = ssrc[i + e];
                u[e] = *(const uint4*)&linbf[(size_t)s * OUT_CH + l * 8];
            }
#pragma unroll
            for (int e = 0; e < 4; ++e) {
                const unsigned* p = (const unsigned*)&u[e];
#pragma unroll
                for (int j = 0; j < 4; ++j) {
                    a[2*j]   += __uint_as_float(p[j] << 16);
                    a[2*j+1] += __uint_as_float(p[j] & 0xffff0000u);
                }
            }
        }
        for (; i < end; ++i) {
            int s = ssrc[i];
            uint4 u0 = *(const uint4*)&linbf[(size_t)s * OUT_CH + l * 8];
            const unsigned* p0 = (const unsigned*)&u0;
#pragma unroll
            for (int j = 0; j < 4; ++j) {
                a[2*j]   += __uint_as_float(p0[j] << 16);
                a[2*j+1] += __uint_as_float(p0[j] & 0xffff0000u);
            }
        }
        float inv = 1.0f / (float)(deg > 1 ? deg : 1);
        float4 o0, o1;
        o0.x = a[0]*inv; o0.y = a[1]*inv; o0.z = a[2]*inv; o0.w = a[3]*inv;
        o1.x = a[4]*inv; o1.y = a[5]*inv; o1.z = a[6]*inv; o1.w = a[7]*inv;
        float* op = &out[(size_t)n * OUT_CH + l * 8];
        ((float4*)op)[0] = o0;
        ((float4*)op)[1] = o1;
    }
}

extern "C" void kernel_launch(void* const* d_in, const int* in_sizes, int n_in,
                              void* d_out, int out_size, void* d_ws, size_t ws_size,
                              hipStream_t stream) {
    const float* x  = (const float*)d_in[0];
    const int*   ei = (const int*)d_in[1];     // [2][E]: src then dst
    const float* W  = (const float*)d_in[2];
    const float* b  = (const float*)d_in[3];
    float* out = (float*)d_out;

    const int* src = ei;
    const int* dst = ei + N_EDGES;

    // workspace: linbf 12.8MB | Wbf 64KB | rec 4.8MB | bcnt
    char* ws = (char*)d_ws;
    short*    linbf = (short*)ws;    ws += ((size_t)N_NODES * OUT_CH * sizeof(short) + 255) & ~255ull;
    short*    Wbf   = (short*)ws;    ws += ((size_t)IN_CH * OUT_CH * sizeof(short) + 255) & ~255ull;
    unsigned* rec   = (unsigned*)ws; ws += ((size_t)NB * CAP * sizeof(unsigned) + 255) & ~255ull;
    int*      bcnt  = (int*)ws;

    convert_w<<<16, 256, 0, stream>>>(W, Wbf, bcnt);
    gemm_bucket<<<NGEMM + NB, 256, 0, stream>>>(x, Wbf, b, linbf, src, dst, bcnt, rec);
    fine_gather<<<NB, FG_THR, 0, stream>>>(bcnt, rec, linbf, out);
}